// Round 10
// baseline (377.818 us; speedup 1.0000x reference)
//
#include <hip/hip_runtime.h>

#define BATCH 32
#define NPTS  1024
#define NTOT  (BATCH * NPTS)   // 32768 points

typedef _Float16 half8  __attribute__((ext_vector_type(8)));
typedef _Float16 half2v __attribute__((ext_vector_type(2)));
typedef float    f32x4  __attribute__((ext_vector_type(4)));

// ---------- helpers ----------

__device__ __forceinline__ float fast_tanh(float x) {
  float ax = fabsf(x);
  float e  = __expf(-2.0f * ax);
  float t  = (1.0f - e) / (1.0f + e);
  return x < 0.0f ? -t : t;
}

// Jacobi polys for a=b=1, degree 3: p1=2t, p2=3.75t^2-0.75, p3=7t^3-3t
__device__ __forceinline__ void jacobi4(float t, float& p0, float& p1, float& p2, float& p3) {
  float t2 = t * t;
  p0 = 1.0f;
  p1 = 2.0f * t;
  p2 = 3.75f * t2 - 0.75f;
  p3 = t * (7.0f * t2 - 3.0f);
}

// monotone float<->uint encoding for atomicMax over signed floats
__device__ __forceinline__ unsigned encf(float f) {
  unsigned b = __float_as_uint(f);
  return b ^ ((unsigned)((int)b >> 31) | 0x80000000u);
}
__device__ __forceinline__ float decf(unsigned u) {
  unsigned b = (u & 0x80000000u) ? (u ^ 0x80000000u) : ~u;
  return __uint_as_float(b);
}

// ---------- zero workspace accumulators ----------
__global__ void zero_ws(unsigned* __restrict__ p, int n) {
  int i = blockIdx.x * 256 + threadIdx.x;
  if (i < n) p[i] = 0u;
}

// ---------- weight preconversion (slot layout, p0..p3), x64 scaled ----------
__global__ void conv_w16(const float* __restrict__ w, half8* __restrict__ wh,
                         int C_in, int C_out, int BN) {
  const int nslot = C_in >> 1;
  int tid = blockIdx.x * 256 + threadIdx.x;
  int oL = tid % BN;
  int r  = tid / BN;
  int s  = r % nslot;
  int ot = r / nslot;
  int i  = s << 1;
  int o  = ot * BN + oL;
  const float4 wa = *(const float4*)(w + (((size_t)i * C_out + o) << 2));
  const float4 wb = *(const float4*)(w + (((size_t)(i + 1) * C_out + o) << 2));
  half8 h;
  h[0] = (_Float16)(wa.x * 64.0f); h[1] = (_Float16)(wa.y * 64.0f);
  h[2] = (_Float16)(wa.z * 64.0f); h[3] = (_Float16)(wa.w * 64.0f);
  h[4] = (_Float16)(wb.x * 64.0f); h[5] = (_Float16)(wb.y * 64.0f);
  h[6] = (_Float16)(wb.z * 64.0f); h[7] = (_Float16)(wb.w * 64.0f);
  wh[tid] = h;
}

// ---------- activation pass: y (fp32, pre-BN) -> T16 packed fp16 tanh pairs ----------
// T16[(b*nslot + s)*1024 + n] = u32{ fp16 t(ch 2s), fp16 t(ch 2s+1) }
__global__ __launch_bounds__(256) void act_tanh16(
    const float* __restrict__ y, const float2* __restrict__ st,
    unsigned* __restrict__ T16, int C)
{
  const int nslot = C >> 1;
  const int b  = blockIdx.x / nslot;
  const int s  = blockIdx.x - b * nslot;
  const int n  = threadIdx.x << 2;
  const float* yp = y + (((size_t)(b * C + (s << 1))) << 10) + n;
  const float2 s0 = st[(s << 1)];
  const float2 s1 = st[(s << 1) + 1];
  float4 v0 = *(const float4*)yp;
  float4 v1 = *(const float4*)(yp + 1024);
  float a0[4] = {v0.x, v0.y, v0.z, v0.w};
  float a1[4] = {v1.x, v1.y, v1.z, v1.w};
  unsigned r[4];
#pragma unroll
  for (int k = 0; k < 4; ++k) {
    _Float16 h0 = (_Float16)fast_tanh((a0[k] - s0.x) * s0.y);
    _Float16 h1 = (_Float16)fast_tanh((a1[k] - s1.x) * s1.y);
    unsigned lo = (unsigned)__builtin_bit_cast(unsigned short, h0);
    unsigned hi = (unsigned)__builtin_bit_cast(unsigned short, h1);
    r[k] = lo | (hi << 16);
  }
  *(uint4*)(T16 + (((size_t)(b * nslot + s)) << 10) + n) = make_uint4(r[0], r[1], r[2], r[3]);
}

// ---------- MFMA KAN layer v7d: fp16 T input, packed-fp16 poly, DEPTH-buffer prefetch ----------
// DEPTH=2 for tiny layers (L2/L3); DEPTH=4 for all NBW=2 layers (L4-L9): real
// residency is ~2 waves/SIMD (76 VGPR + 64 AGPR acc), so latency must be ILP-hidden.
// Runtime loop + named stage sets preserves prefetch distance (R3 pattern; full
// unroll collapses it, R4 lesson; depth-4 on L7/L8/L9 verified +16 us in R9).
template<int NBW, int DEPTH>
__global__ __launch_bounds__(NBW * 128, 2) void kan_mfma7(
    const unsigned* __restrict__ T16,  // (B, nslot, N) packed fp16 tanh pairs
    const half8* __restrict__ wh,
    const float* __restrict__ bias,    // (B, C_out) or nullptr
    float*       __restrict__ out,     // (B, C_out, N) fp32 or nullptr (L5 mode)
    float2*      __restrict__ spart,
    float*       __restrict__ stat_acc,
    unsigned*    __restrict__ max_acc,
    int C_in, int C_out)
{
  constexpr int BN = NBW * 64;
  const int nslot = C_in >> 1;
  __shared__ float sredS[BN][2], sredS2[BN][2], sredM[BN][2];

  const int t    = threadIdx.x;
  const int lane = t & 63;
  const int col  = lane & 15;
  const int quad = lane >> 4;
  const int wv   = t >> 6;
  const int wm   = wv & 1;
  const int wn   = wv >> 1;
  const int b    = blockIdx.x >> 3;
  const int n0   = (blockIdx.x & 7) << 7;
  const int o0   = blockIdx.y * BN;

  f32x4 acc[4][4];
#pragma unroll
  for (int i = 0; i < 4; ++i)
#pragma unroll
    for (int j = 0; j < 4; ++j)
#pragma unroll
      for (int k = 0; k < 4; ++k) acc[i][j][k] = 0.0f;

  const unsigned* Tp = T16 + (((size_t)(b * nslot + quad)) << 10) + n0 + (wm << 6) + col;
  const half8*    Bp = wh + (size_t)blockIdx.y * nslot * BN + (size_t)quad * BN + wn * 64 + col;

  const half2v c375  = {(_Float16)3.75f,  (_Float16)3.75f};
  const half2v cm075 = {(_Float16)-0.75f, (_Float16)-0.75f};
  const half2v c70   = {(_Float16)7.0f,   (_Float16)7.0f};
  const half2v cm30  = {(_Float16)-3.0f,  (_Float16)-3.0f};

  // one K-step = 4 slots (8 channels); A advance 4 rows x 1024 u32 = J<<12,
  // B advance 4 rows x BN half8.
#define KLOAD(TTR, BFR, J) do {                                            \
    const unsigned* tp_ = Tp + (((size_t)(unsigned)(J)) << 12);            \
    const half8*    bp_ = Bp + (size_t)(unsigned)(J) * (BN << 2);          \
    TTR[0] = tp_[0];  TTR[1] = tp_[16];                                    \
    TTR[2] = tp_[32]; TTR[3] = tp_[48];                                    \
    BFR[0] = bp_[0];  BFR[1] = bp_[16];                                    \
    BFR[2] = bp_[32]; BFR[3] = bp_[48];                                    \
  } while (0)

#define KSTEP(TTR, BFR) do {                                               \
    half8 af_[4];                                                          \
    _Pragma("unroll")                                                      \
    for (int fm_ = 0; fm_ < 4; ++fm_) {                                    \
      half2v tt = __builtin_bit_cast(half2v, TTR[fm_]);                    \
      half2v t2 = tt * tt;                                                 \
      half2v q1 = tt + tt;                                                 \
      half2v q2 = t2 * c375 + cm075;                                       \
      half2v q3 = tt * (t2 * c70 + cm30);                                  \
      half8 h;                                                             \
      h[0] = (_Float16)1.0f; h[1] = q1[0]; h[2] = q2[0]; h[3] = q3[0];     \
      h[4] = (_Float16)1.0f; h[5] = q1[1]; h[6] = q2[1]; h[7] = q3[1];     \
      af_[fm_] = h;                                                        \
    }                                                                      \
    _Pragma("unroll")                                                      \
    for (int fm_ = 0; fm_ < 4; ++fm_) {                                    \
      _Pragma("unroll")                                                    \
      for (int fn_ = 0; fn_ < 4; ++fn_)                                    \
        acc[fm_][fn_] = __builtin_amdgcn_mfma_f32_16x16x32_f16(            \
            af_[fm_], BFR[fn_], acc[fm_][fn_], 0, 0, 0);                   \
    }                                                                      \
  } while (0)

  const int nIt = nslot >> 2;   // 8 / 16 / 32 / 64 — all % 4 == 0
  if constexpr (DEPTH == 2) {
    unsigned ttA[4], ttB[4];
    half8    bfA[4], bfB[4];
    KLOAD(ttA, bfA, 0);
    KLOAD(ttB, bfB, 1);
    int it = 0;
    for (; it + 3 < nIt; it += 2) {
      KSTEP(ttA, bfA); KLOAD(ttA, bfA, it + 2);
      KSTEP(ttB, bfB); KLOAD(ttB, bfB, it + 3);
    }
    KSTEP(ttA, bfA);
    KSTEP(ttB, bfB);
  } else {
    unsigned ttA[4], ttB[4], ttC[4], ttD[4];
    half8    bfA[4], bfB[4], bfC[4], bfD[4];
    KLOAD(ttA, bfA, 0);
    KLOAD(ttB, bfB, 1);
    KLOAD(ttC, bfC, 2);
    KLOAD(ttD, bfD, 3);
    int it = 0;
    for (; it + 7 < nIt; it += 4) {
      KSTEP(ttA, bfA); KLOAD(ttA, bfA, it + 4);
      KSTEP(ttB, bfB); KLOAD(ttB, bfB, it + 5);
      KSTEP(ttC, bfC); KLOAD(ttC, bfC, it + 6);
      KSTEP(ttD, bfD); KLOAD(ttD, bfD, it + 7);
    }
    KSTEP(ttA, bfA);
    KSTEP(ttB, bfB);
    KSTEP(ttC, bfC);
    KSTEP(ttD, bfD);
  }

#undef KLOAD
#undef KSTEP

  const float inv64 = 0.015625f;
#pragma unroll
  for (int fn = 0; fn < 4; ++fn) {
    const int cl = (wn << 6) + (fn << 4) + col;
    const int o  = o0 + cl;
    const float bb = bias ? bias[b * C_out + o] : 0.0f;
    float s = 0.f, s2 = 0.f, mx = -3.4e38f;
#pragma unroll
    for (int fm = 0; fm < 4; ++fm) {
      float v0 = acc[fm][fn][0] * inv64 + bb;
      float v1 = acc[fm][fn][1] * inv64 + bb;
      float v2 = acc[fm][fn][2] * inv64 + bb;
      float v3 = acc[fm][fn][3] * inv64 + bb;
      if (out) {
        *(float4*)(out + (((size_t)(b * C_out + o)) << 10) + n0 + (wm << 6) + (fm << 4) + (quad << 2)) =
            make_float4(v0, v1, v2, v3);
      }
      s  += v0 + v1 + v2 + v3;
      s2 += v0 * v0 + v1 * v1 + v2 * v2 + v3 * v3;
      mx  = fmaxf(fmaxf(v0, v1), fmaxf(fmaxf(v2, v3), mx));
    }
    s  += __shfl_down(s, 32);  s  += __shfl_down(s, 16);
    s2 += __shfl_down(s2, 32); s2 += __shfl_down(s2, 16);
    mx  = fmaxf(mx, __shfl_down(mx, 32)); mx = fmaxf(mx, __shfl_down(mx, 16));
    if (lane < 16) {
      sredS [cl][wm] = s;
      sredS2[cl][wm] = s2;
      sredM [cl][wm] = mx;
    }
  }
  __syncthreads();
  if (t < BN) {
    const int o = o0 + t;
    float s  = sredS [t][0] + sredS [t][1];
    float s2 = sredS2[t][0] + sredS2[t][1];
    if (out) {
      spart[(o << 8) + blockIdx.x] = make_float2(s, s2);
    } else {
      float mx = fmaxf(sredM[t][0], sredM[t][1]);
      atomicAdd(&stat_acc[o], s);
      atomicAdd(&stat_acc[C_out + o], s2);
      atomicMax(&max_acc[b * C_out + o], encf(mx));
    }
  }
}

// ---------- fp32 KAN layer (L1 only: C_in=2) ----------
template<int BM, int BN>
__global__ __launch_bounds__(256) void kan_gemm(
    const float*  __restrict__ in, const float2* __restrict__ stats,
    const float*  __restrict__ w, float* __restrict__ out,
    float2* __restrict__ spart, int C_in, int C_out)
{
  static_assert(BM * BN == 256 * 64, "8x8-per-thread tile requires BM*BN == 16384");
  constexpr int TM = BM / 8;
  constexpr int AE = 8 * BM / 256;
  constexpr int BE = 8 * BN / 256;
  __shared__ __align__(16) float As[32][BM];
  __shared__ __align__(16) float Bs[32][BN];

  const int t  = threadIdx.x;
  const int tpb = NPTS / BM;
  const int b  = blockIdx.x / tpb;
  const int n0 = (blockIdx.x % tpb) * BM;
  const int o0 = blockIdx.y * BN;
  const int tm = t % TM;
  const int to = t / TM;

  float acc[2][4][2][4];
#pragma unroll
  for (int a = 0; a < 2; ++a)
#pragma unroll
    for (int c = 0; c < 4; ++c)
#pragma unroll
      for (int d = 0; d < 2; ++d)
#pragma unroll
        for (int e = 0; e < 4; ++e) acc[a][c][d][e] = 0.0f;

  const int nch = (C_in + 7) >> 3;
  for (int ch = 0; ch < nch; ++ch) {
    const int i0 = ch << 3;
    __syncthreads();
#pragma unroll
    for (int r = 0; r < AE; ++r) {
      int e  = t + (r << 8);
      int il = e / BM, n = e % BM;
      int i  = i0 + il;
      float p0 = 0.f, p1 = 0.f, p2 = 0.f, p3 = 0.f;
      if (i < C_in) {
        float v = in[((size_t)(b * C_in + i) << 10) + n0 + n];
        if (stats) { float2 s = stats[i]; v = (v - s.x) * s.y; }
        jacobi4(fast_tanh(v), p0, p1, p2, p3);
      }
      As[(il << 2) + 0][n] = p0;
      As[(il << 2) + 1][n] = p1;
      As[(il << 2) + 2][n] = p2;
      As[(il << 2) + 3][n] = p3;
    }
#pragma unroll
    for (int r = 0; r < BE; ++r) {
      int e  = t + (r << 8);
      int il = e / BN, o = e % BN;
      int i  = i0 + il;
      float4 wv = make_float4(0.f, 0.f, 0.f, 0.f);
      if (i < C_in) wv = *(const float4*)(w + (((size_t)i * C_out + o0 + o) << 2));
      Bs[(il << 2) + 0][o] = wv.x;
      Bs[(il << 2) + 1][o] = wv.y;
      Bs[(il << 2) + 2][o] = wv.z;
      Bs[(il << 2) + 3][o] = wv.w;
    }
    __syncthreads();
#pragma unroll 8
    for (int k = 0; k < 32; ++k) {
      const float4 a0 = *(const float4*)&As[k][tm << 2];
      const float4 a1 = *(const float4*)&As[k][(BM / 2) + (tm << 2)];
      const float4 b0 = *(const float4*)&Bs[k][to << 2];
      const float4 b1 = *(const float4*)&Bs[k][(BN / 2) + (to << 2)];
      const float am[2][4] = {{a0.x, a0.y, a0.z, a0.w}, {a1.x, a1.y, a1.z, a1.w}};
      const float bo[2][4] = {{b0.x, b0.y, b0.z, b0.w}, {b1.x, b1.y, b1.z, b1.w}};
#pragma unroll
      for (int oh = 0; oh < 2; ++oh)
#pragma unroll
        for (int oj = 0; oj < 4; ++oj) {
          const float bv = bo[oh][oj];
#pragma unroll
          for (int mh = 0; mh < 2; ++mh)
#pragma unroll
            for (int mj = 0; mj < 4; ++mj)
              acc[oh][oj][mh][mj] = fmaf(bv, am[mh][mj], acc[oh][oj][mh][mj]);
        }
    }
  }

#pragma unroll
  for (int oh = 0; oh < 2; ++oh)
#pragma unroll
    for (int oj = 0; oj < 4; ++oj) {
      const int o = o0 + oh * (BN / 2) + (to << 2) + oj;
      float s = 0.f, s2 = 0.f;
#pragma unroll
      for (int mh = 0; mh < 2; ++mh) {
        float4 v = make_float4(acc[oh][oj][mh][0], acc[oh][oj][mh][1],
                               acc[oh][oj][mh][2], acc[oh][oj][mh][3]);
        *(float4*)(out + (((size_t)(b * C_out + o)) << 10) + n0 + mh * (BM / 2) + (tm << 2)) = v;
        s  += v.x + v.y + v.z + v.w;
        s2 += v.x * v.x + v.y * v.y + v.z * v.z + v.w * v.w;
      }
#pragma unroll
      for (int off = TM / 2; off > 0; off >>= 1) {
        s  += __shfl_down(s, off, TM);
        s2 += __shfl_down(s2, off, TM);
      }
      if (tm == 0) spart[(o << 8) + blockIdx.x] = make_float2(s, s2);
    }
}

// ---------- reduce per-block partials -> BN stats ----------
__global__ __launch_bounds__(256) void bn_finalize2(
    const float2* __restrict__ spart, float2* __restrict__ stats, int C, int nxb)
{
  int c = blockIdx.x, t = threadIdx.x;
  float s = 0.f, s2 = 0.f;
  if (t < nxb) { float2 p = spart[(c << 8) + t]; s = p.x; s2 = p.y; }
#pragma unroll
  for (int off = 32; off > 0; off >>= 1) {
    s  += __shfl_down(s, off);
    s2 += __shfl_down(s2, off);
  }
  __shared__ float rs[4], rs2[4];
  int wid = t >> 6;
  if ((t & 63) == 0) { rs[wid] = s; rs2[wid] = s2; }
  __syncthreads();
  if (t == 0) {
    s  = rs[0] + rs[1] + rs[2] + rs[3];
    s2 = rs2[0] + rs2[1] + rs2[2] + rs2[3];
    float m   = s * (1.0f / NTOT);
    float var = s2 * (1.0f / NTOT) - m * m;
    stats[c] = make_float2(m, rsqrtf(var + 1e-5f));
  }
}

// ---------- finalize layer-5 stats from atomic accumulators ----------
__global__ void bn_finalize(const float* __restrict__ stat_acc,
                            float2* __restrict__ stats, int C) {
  int c = blockIdx.x * 256 + threadIdx.x;
  if (c < C) {
    float m   = stat_acc[c] * (1.0f / NTOT);
    float var = stat_acc[C + c] * (1.0f / NTOT) - m * m;
    stats[c] = make_float2(m, rsqrtf(var + 1e-5f));
  }
}

// ---------- global-feature branch of layer 6, parallel ----------
__global__ __launch_bounds__(256) void pool_const6p(
    const unsigned* __restrict__ max_acc, const float2* __restrict__ stats5,
    const float* __restrict__ w6, float* __restrict__ cst)
{
  __shared__ __align__(16) float4 P[32][64];
  const int t  = threadIdx.x;
  const int ot = blockIdx.x;
  const int c0 = blockIdx.y << 6;
#pragma unroll
  for (int it = 0; it < 8; ++it) {
    int idx = t + (it << 8);
    int b = idx >> 6, cl = idx & 63;
    int c = c0 + cl;
    float mx = decf(max_acc[(b << 10) + c]);
    float2 s = stats5[c];
    float tt = fast_tanh((mx - s.x) * s.y);
    float p0, p1, p2, p3; jacobi4(tt, p0, p1, p2, p3);
    P[b][cl] = make_float4(p0, p1, p2, p3);
  }
  __syncthreads();
  const int oL = t & 63;
  const int bg = t >> 6;
  const int o  = (ot << 6) + oL;
  float acc[8];
#pragma unroll
  for (int i = 0; i < 8; ++i) acc[i] = 0.f;
  for (int cl = 0; cl < 64; ++cl) {
    const float4 wv = *(const float4*)(w6 + (((size_t)(64 + c0 + cl) * 512 + o) << 2));
#pragma unroll
    for (int bb = 0; bb < 8; ++bb) {
      float4 p = P[(bg << 3) + bb][cl];
      acc[bb] += p.x * wv.x + p.y * wv.y + p.z * wv.z + p.w * wv.w;
    }
  }
#pragma unroll
  for (int bb = 0; bb < 8; ++bb)
    atomicAdd(&cst[(((bg << 3) + bb) << 9) + o], acc[bb]);
}

// ---------- final layer: C_in=128 fp32 -> C_out=3 fp32 ----------
__global__ __launch_bounds__(256) void kan_final(
    const float* __restrict__ in, const float2* __restrict__ stats,
    const float* __restrict__ w, float* __restrict__ out)
{
  int g = blockIdx.x * 256 + threadIdx.x;
  int b = g >> 10, n = g & 1023;
  float a0 = 0.f, a1 = 0.f, a2 = 0.f;
  for (int i = 0; i < 128; ++i) {
    float v = in[((size_t)(b * 128 + i) << 10) + n];
    float2 s = stats[i];
    float p0, p1, p2, p3; jacobi4(fast_tanh((v - s.x) * s.y), p0, p1, p2, p3);
    const float4 w0 = *(const float4*)(w + ((i * 3 + 0) << 2));
    const float4 w1 = *(const float4*)(w + ((i * 3 + 1) << 2));
    const float4 w2 = *(const float4*)(w + ((i * 3 + 2) << 2));
    a0 += p0 * w0.x + p1 * w0.y + p2 * w0.z + p3 * w0.w;
    a1 += p0 * w1.x + p1 * w1.y + p2 * w1.z + p3 * w1.w;
    a2 += p0 * w2.x + p1 * w2.y + p2 * w2.z + p3 * w2.w;
  }
  out[((b * 3 + 0) << 10) + n] = a0;
  out[((b * 3 + 1) << 10) + n] = a1;
  out[((b * 3 + 2) << 10) + n] = a2;
}

// ---------- launch ----------
extern "C" void kernel_launch(void* const* d_in, const int* in_sizes, int n_in,
                              void* d_out, int out_size, void* d_ws, size_t ws_size,
                              hipStream_t stream) {
  const float* x   = (const float*)d_in[0];
  const float* w1  = (const float*)d_in[1];
  const float* w2  = (const float*)d_in[2];
  const float* w3  = (const float*)d_in[3];
  const float* w4  = (const float*)d_in[4];
  const float* w5  = (const float*)d_in[5];
  const float* w6  = (const float*)d_in[6];
  const float* w7  = (const float*)d_in[7];
  const float* w8  = (const float*)d_in[8];
  const float* w9  = (const float*)d_in[9];
  const float* w10 = (const float*)d_in[10];

  float* ws = (float*)d_ws;
  // misc region (floats)
  float*    stat_acc = ws + 0;                      // 2048
  unsigned* maxenc   = (unsigned*)(ws + 2048);      // 32768
  float*    cst6     = ws + 34816;                  // 16384 (zeroed)
  float2*   spart    = (float2*)(ws + 51200);       // 131072 float2 -> ends 313344
  float2*   stats1   = (float2*)(ws + 313344);
  float2*   stats2   = stats1 + 64;
  float2*   stats3   = stats2 + 64;
  float2*   stats4   = stats3 + 64;
  float2*   stats5   = stats4 + 128;
  float2*   stats6   = stats5 + 1024;
  float2*   stats7   = stats6 + 512;
  float2*   stats8   = stats7 + 256;
  float2*   stats9   = stats8 + 128;
  // fp16 weight pool (half8 units) @ float offset 318464 (same as proven fallback)
  half8*    whbase = (half8*)(ws + 318464);
  half8*    h2 = whbase + 0;        // 32*64    = 2048
  half8*    h3 = whbase + 2048;     // 2048
  half8*    h4 = whbase + 4096;     // 32*128   = 4096
  half8*    h5 = whbase + 8192;     // 64*1024  = 65536
  half8*    h6 = whbase + 73728;    // 32*512   = 16384
  half8*    h7 = whbase + 90112;    // 256*256  = 65536
  half8*    h8 = whbase + 155648;   // 128*128  = 16384
  half8*    h9 = whbase + 172032;   // 64*128   = 8192  -> ends 720896 floats
  // data pool, liveness-aliased (units of MF = 1048576 floats; T16 sizes count u32 = float):
  //   T2:[0,1) act2..L6k | y1:[1,3) | T1:[3,4) | y2:[1,3) | y3:[1,3) | T3:[3,4)
  //   y4:[4,8) | T4:[1,3) | y6:[3,19) | T6:[19,27) | y7:[0,8) | T7:[8,12)
  //   y8:[0,4) | T8:[4,6) | y9:[12,16)      peak 27 MF -> total 28 MF = 112 MB
  const size_t MF = 1048576;
  float*    P   = ws + MF;
  unsigned* T2  = (unsigned*)(P + 0 * MF);
  float*    y1  = P + 1 * MF;
  unsigned* T1  = (unsigned*)(P + 3 * MF);
  float*    y2  = P + 1 * MF;
  float*    y3  = P + 1 * MF;
  unsigned* T3  = (unsigned*)(P + 3 * MF);
  float*    y4  = P + 4 * MF;
  unsigned* T4  = (unsigned*)(P + 1 * MF);
  float*    y6  = P + 3 * MF;
  unsigned* T6  = (unsigned*)(P + 19 * MF);
  float*    y7  = P + 0 * MF;
  unsigned* T7  = (unsigned*)(P + 8 * MF);
  float*    y8  = P + 0 * MF;
  unsigned* T8  = (unsigned*)(P + 4 * MF);
  float*    y9  = P + 12 * MF;

  dim3 blk(256);
  zero_ws<<<200, blk, 0, stream>>>((unsigned*)ws, 51200);
  // preconvert weights (x64, slot layout)
  conv_w16<<<8,   blk, 0, stream>>>(w2, h2, 64, 64, 64);
  conv_w16<<<8,   blk, 0, stream>>>(w3, h3, 64, 64, 64);
  conv_w16<<<16,  blk, 0, stream>>>(w4, h4, 64, 128, 128);
  conv_w16<<<256, blk, 0, stream>>>(w5, h5, 128, 1024, 128);
  conv_w16<<<64,  blk, 0, stream>>>(w6, h6, 64, 512, 128);   // local rows 0..63
  conv_w16<<<256, blk, 0, stream>>>(w7, h7, 512, 256, 128);
  conv_w16<<<64,  blk, 0, stream>>>(w8, h8, 256, 128, 128);
  conv_w16<<<32,  blk, 0, stream>>>(w9, h9, 128, 128, 128);

  // L1: 2 -> 64 fp32
  kan_gemm<256, 64><<<dim3(128, 1), blk, 0, stream>>>(x, nullptr, w1, y1, spart, 2, 64);
  bn_finalize2<<<64, blk, 0, stream>>>(spart, stats1, 64, 128);
  act_tanh16<<<32 * 32, blk, 0, stream>>>(y1, stats1, T1, 64);
  // L2: 64 -> 64
  kan_mfma7<1, 2><<<dim3(256, 1), 128, 0, stream>>>(T1, h2, nullptr, y2, spart, nullptr, nullptr, 64, 64);
  bn_finalize2<<<64, blk, 0, stream>>>(spart, stats2, 64, 256);
  act_tanh16<<<32 * 32, blk, 0, stream>>>(y2, stats2, T2, 64);   // T2 kept for L6
  // L3: 64 -> 64
  kan_mfma7<1, 2><<<dim3(256, 1), 128, 0, stream>>>(T2, h3, nullptr, y3, spart, nullptr, nullptr, 64, 64);
  bn_finalize2<<<64, blk, 0, stream>>>(spart, stats3, 64, 256);
  act_tanh16<<<32 * 32, blk, 0, stream>>>(y3, stats3, T3, 64);
  // L4: 64 -> 128 (depth 4)
  kan_mfma7<2, 4><<<dim3(256, 1), blk, 0, stream>>>(T3, h4, nullptr, y4, spart, nullptr, nullptr, 64, 128);
  bn_finalize2<<<128, blk, 0, stream>>>(spart, stats4, 128, 256);
  act_tanh16<<<32 * 64, blk, 0, stream>>>(y4, stats4, T4, 128);
  // L5: 128 -> 1024, fused stats + maxpool, no materialization (depth 4)
  kan_mfma7<2, 4><<<dim3(256, 8), blk, 0, stream>>>(T4, h5, nullptr, nullptr, nullptr, stat_acc, maxenc, 128, 1024);
  bn_finalize<<<4, blk, 0, stream>>>(stat_acc, stats5, 1024);
  // gf branch of layer 6
  pool_const6p<<<dim3(8, 16), blk, 0, stream>>>(maxenc, stats5, w6, cst6);
  // L6: 64 (local, T2) -> 512 + gf bias (depth 4)
  kan_mfma7<2, 4><<<dim3(256, 4), blk, 0, stream>>>(T2, h6, cst6, y6, spart, nullptr, nullptr, 64, 512);
  bn_finalize2<<<512, blk, 0, stream>>>(spart, stats6, 512, 256);
  act_tanh16<<<32 * 256, blk, 0, stream>>>(y6, stats6, T6, 512);
  // L7: 512 -> 256 (depth 4)
  kan_mfma7<2, 4><<<dim3(256, 2), blk, 0, stream>>>(T6, h7, nullptr, y7, spart, nullptr, nullptr, 512, 256);
  bn_finalize2<<<256, blk, 0, stream>>>(spart, stats7, 256, 256);
  act_tanh16<<<32 * 128, blk, 0, stream>>>(y7, stats7, T7, 256);
  // L8: 256 -> 128 (depth 4)
  kan_mfma7<2, 4><<<dim3(256, 1), blk, 0, stream>>>(T7, h8, nullptr, y8, spart, nullptr, nullptr, 256, 128);
  bn_finalize2<<<128, blk, 0, stream>>>(spart, stats8, 128, 256);
  act_tanh16<<<32 * 64, blk, 0, stream>>>(y8, stats8, T8, 128);
  // L9: 128 -> 128 (depth 4)
  kan_mfma7<2, 4><<<dim3(256, 1), blk, 0, stream>>>(T8, h9, nullptr, y9, spart, nullptr, nullptr, 128, 128);
  bn_finalize2<<<128, blk, 0, stream>>>(spart, stats9, 128, 256);
  // L10: 128 -> 3 (tanh+Jacobi inline, fp32)
  kan_final<<<128, blk, 0, stream>>>(y9, stats9, w10, (float*)d_out);
}

// Round 11
// 376.780 us; speedup vs baseline: 1.0028x; 1.0028x over previous
//
#include <hip/hip_runtime.h>

#define BATCH 32
#define NPTS  1024
#define NTOT  (BATCH * NPTS)   // 32768 points

typedef _Float16 half8  __attribute__((ext_vector_type(8)));
typedef _Float16 half2v __attribute__((ext_vector_type(2)));
typedef float    f32x4  __attribute__((ext_vector_type(4)));

// ---------- helpers ----------

__device__ __forceinline__ float fast_tanh(float x) {
  float ax = fabsf(x);
  float e  = __expf(-2.0f * ax);
  float t  = (1.0f - e) / (1.0f + e);
  return x < 0.0f ? -t : t;
}

// Jacobi polys for a=b=1, degree 3: p1=2t, p2=3.75t^2-0.75, p3=7t^3-3t
__device__ __forceinline__ void jacobi4(float t, float& p0, float& p1, float& p2, float& p3) {
  float t2 = t * t;
  p0 = 1.0f;
  p1 = 2.0f * t;
  p2 = 3.75f * t2 - 0.75f;
  p3 = t * (7.0f * t2 - 3.0f);
}

// monotone float<->uint encoding for atomicMax over signed floats
__device__ __forceinline__ unsigned encf(float f) {
  unsigned b = __float_as_uint(f);
  return b ^ ((unsigned)((int)b >> 31) | 0x80000000u);
}
__device__ __forceinline__ float decf(unsigned u) {
  unsigned b = (u & 0x80000000u) ? (u ^ 0x80000000u) : ~u;
  return __uint_as_float(b);
}

// ---------- zero workspace accumulators ----------
__global__ void zero_ws(unsigned* __restrict__ p, int n) {
  int i = blockIdx.x * 256 + threadIdx.x;
  if (i < n) p[i] = 0u;
}

// ---------- weight preconversion (slot layout, p0..p3), x64 scaled ----------
__global__ void conv_w16(const float* __restrict__ w, half8* __restrict__ wh,
                         int C_in, int C_out, int BN) {
  const int nslot = C_in >> 1;
  int tid = blockIdx.x * 256 + threadIdx.x;
  int oL = tid % BN;
  int r  = tid / BN;
  int s  = r % nslot;
  int ot = r / nslot;
  int i  = s << 1;
  int o  = ot * BN + oL;
  const float4 wa = *(const float4*)(w + (((size_t)i * C_out + o) << 2));
  const float4 wb = *(const float4*)(w + (((size_t)(i + 1) * C_out + o) << 2));
  half8 h;
  h[0] = (_Float16)(wa.x * 64.0f); h[1] = (_Float16)(wa.y * 64.0f);
  h[2] = (_Float16)(wa.z * 64.0f); h[3] = (_Float16)(wa.w * 64.0f);
  h[4] = (_Float16)(wb.x * 64.0f); h[5] = (_Float16)(wb.y * 64.0f);
  h[6] = (_Float16)(wb.z * 64.0f); h[7] = (_Float16)(wb.w * 64.0f);
  wh[tid] = h;
}

// ---------- activation pass: y (fp32, pre-BN) -> T16 packed fp16 tanh pairs ----------
// T16[(b*nslot + s)*1024 + n] = u32{ fp16 t(ch 2s), fp16 t(ch 2s+1) }
__global__ __launch_bounds__(256) void act_tanh16(
    const float* __restrict__ y, const float2* __restrict__ st,
    unsigned* __restrict__ T16, int C)
{
  const int nslot = C >> 1;
  const int b  = blockIdx.x / nslot;
  const int s  = blockIdx.x - b * nslot;
  const int n  = threadIdx.x << 2;
  const float* yp = y + (((size_t)(b * C + (s << 1))) << 10) + n;
  const float2 s0 = st[(s << 1)];
  const float2 s1 = st[(s << 1) + 1];
  float4 v0 = *(const float4*)yp;
  float4 v1 = *(const float4*)(yp + 1024);
  float a0[4] = {v0.x, v0.y, v0.z, v0.w};
  float a1[4] = {v1.x, v1.y, v1.z, v1.w};
  unsigned r[4];
#pragma unroll
  for (int k = 0; k < 4; ++k) {
    _Float16 h0 = (_Float16)fast_tanh((a0[k] - s0.x) * s0.y);
    _Float16 h1 = (_Float16)fast_tanh((a1[k] - s1.x) * s1.y);
    unsigned lo = (unsigned)__builtin_bit_cast(unsigned short, h0);
    unsigned hi = (unsigned)__builtin_bit_cast(unsigned short, h1);
    r[k] = lo | (hi << 16);
  }
  *(uint4*)(T16 + (((size_t)(b * nslot + s)) << 10) + n) = make_uint4(r[0], r[1], r[2], r[3]);
}

// ---------- MFMA KAN layer v7d: fp16 T input, packed-fp16 poly, DEPTH-buffer prefetch ----------
// R9-proven config: DEPTH=2 for TLP-rich layers (L2-L6), DEPTH=4 for grid-limited
// layers (L7/L8/L9). Runtime loop + named stage sets preserves prefetch distance.
template<int NBW, int DEPTH>
__global__ __launch_bounds__(NBW * 128, 2) void kan_mfma7(
    const unsigned* __restrict__ T16,  // (B, nslot, N) packed fp16 tanh pairs
    const half8* __restrict__ wh,
    const float* __restrict__ bias,    // (B, C_out) or nullptr
    float*       __restrict__ out,     // (B, C_out, N) fp32 or nullptr (L5 mode)
    float2*      __restrict__ spart,
    float*       __restrict__ stat_acc,
    unsigned*    __restrict__ max_acc,
    int C_in, int C_out)
{
  constexpr int BN = NBW * 64;
  const int nslot = C_in >> 1;
  __shared__ float sredS[BN][2], sredS2[BN][2], sredM[BN][2];

  const int t    = threadIdx.x;
  const int lane = t & 63;
  const int col  = lane & 15;
  const int quad = lane >> 4;
  const int wv   = t >> 6;
  const int wm   = wv & 1;
  const int wn   = wv >> 1;
  const int b    = blockIdx.x >> 3;
  const int n0   = (blockIdx.x & 7) << 7;
  const int o0   = blockIdx.y * BN;

  f32x4 acc[4][4];
#pragma unroll
  for (int i = 0; i < 4; ++i)
#pragma unroll
    for (int j = 0; j < 4; ++j)
#pragma unroll
      for (int k = 0; k < 4; ++k) acc[i][j][k] = 0.0f;

  const unsigned* Tp = T16 + (((size_t)(b * nslot + quad)) << 10) + n0 + (wm << 6) + col;
  const half8*    Bp = wh + (size_t)blockIdx.y * nslot * BN + (size_t)quad * BN + wn * 64 + col;

  const half2v c375  = {(_Float16)3.75f,  (_Float16)3.75f};
  const half2v cm075 = {(_Float16)-0.75f, (_Float16)-0.75f};
  const half2v c70   = {(_Float16)7.0f,   (_Float16)7.0f};
  const half2v cm30  = {(_Float16)-3.0f,  (_Float16)-3.0f};

#define KLOAD(TTR, BFR, J) do {                                            \
    const unsigned* tp_ = Tp + (((size_t)(unsigned)(J)) << 12);            \
    const half8*    bp_ = Bp + (size_t)(unsigned)(J) * (BN << 2);          \
    TTR[0] = tp_[0];  TTR[1] = tp_[16];                                    \
    TTR[2] = tp_[32]; TTR[3] = tp_[48];                                    \
    BFR[0] = bp_[0];  BFR[1] = bp_[16];                                    \
    BFR[2] = bp_[32]; BFR[3] = bp_[48];                                    \
  } while (0)

#define KSTEP(TTR, BFR) do {                                               \
    half8 af_[4];                                                          \
    _Pragma("unroll")                                                      \
    for (int fm_ = 0; fm_ < 4; ++fm_) {                                    \
      half2v tt = __builtin_bit_cast(half2v, TTR[fm_]);                    \
      half2v t2 = tt * tt;                                                 \
      half2v q1 = tt + tt;                                                 \
      half2v q2 = t2 * c375 + cm075;                                       \
      half2v q3 = tt * (t2 * c70 + cm30);                                  \
      half8 h;                                                             \
      h[0] = (_Float16)1.0f; h[1] = q1[0]; h[2] = q2[0]; h[3] = q3[0];     \
      h[4] = (_Float16)1.0f; h[5] = q1[1]; h[6] = q2[1]; h[7] = q3[1];     \
      af_[fm_] = h;                                                        \
    }                                                                      \
    _Pragma("unroll")                                                      \
    for (int fm_ = 0; fm_ < 4; ++fm_) {                                    \
      _Pragma("unroll")                                                    \
      for (int fn_ = 0; fn_ < 4; ++fn_)                                    \
        acc[fm_][fn_] = __builtin_amdgcn_mfma_f32_16x16x32_f16(            \
            af_[fm_], BFR[fn_], acc[fm_][fn_], 0, 0, 0);                   \
    }                                                                      \
  } while (0)

  const int nIt = nslot >> 2;   // 8 / 16 / 32 / 64 — all % 4 == 0
  if constexpr (DEPTH == 2) {
    unsigned ttA[4], ttB[4];
    half8    bfA[4], bfB[4];
    KLOAD(ttA, bfA, 0);
    KLOAD(ttB, bfB, 1);
    int it = 0;
    for (; it + 3 < nIt; it += 2) {
      KSTEP(ttA, bfA); KLOAD(ttA, bfA, it + 2);
      KSTEP(ttB, bfB); KLOAD(ttB, bfB, it + 3);
    }
    KSTEP(ttA, bfA);
    KSTEP(ttB, bfB);
  } else {
    unsigned ttA[4], ttB[4], ttC[4], ttD[4];
    half8    bfA[4], bfB[4], bfC[4], bfD[4];
    KLOAD(ttA, bfA, 0);
    KLOAD(ttB, bfB, 1);
    KLOAD(ttC, bfC, 2);
    KLOAD(ttD, bfD, 3);
    int it = 0;
    for (; it + 7 < nIt; it += 4) {
      KSTEP(ttA, bfA); KLOAD(ttA, bfA, it + 4);
      KSTEP(ttB, bfB); KLOAD(ttB, bfB, it + 5);
      KSTEP(ttC, bfC); KLOAD(ttC, bfC, it + 6);
      KSTEP(ttD, bfD); KLOAD(ttD, bfD, it + 7);
    }
    KSTEP(ttA, bfA);
    KSTEP(ttB, bfB);
    KSTEP(ttC, bfC);
    KSTEP(ttD, bfD);
  }

#undef KLOAD
#undef KSTEP

  const float inv64 = 0.015625f;
#pragma unroll
  for (int fn = 0; fn < 4; ++fn) {
    const int cl = (wn << 6) + (fn << 4) + col;
    const int o  = o0 + cl;
    const float bb = bias ? bias[b * C_out + o] : 0.0f;
    float s = 0.f, s2 = 0.f, mx = -3.4e38f;
#pragma unroll
    for (int fm = 0; fm < 4; ++fm) {
      float v0 = acc[fm][fn][0] * inv64 + bb;
      float v1 = acc[fm][fn][1] * inv64 + bb;
      float v2 = acc[fm][fn][2] * inv64 + bb;
      float v3 = acc[fm][fn][3] * inv64 + bb;
      if (out) {
        *(float4*)(out + (((size_t)(b * C_out + o)) << 10) + n0 + (wm << 6) + (fm << 4) + (quad << 2)) =
            make_float4(v0, v1, v2, v3);
      }
      s  += v0 + v1 + v2 + v3;
      s2 += v0 * v0 + v1 * v1 + v2 * v2 + v3 * v3;
      mx  = fmaxf(fmaxf(v0, v1), fmaxf(fmaxf(v2, v3), mx));
    }
    s  += __shfl_down(s, 32);  s  += __shfl_down(s, 16);
    s2 += __shfl_down(s2, 32); s2 += __shfl_down(s2, 16);
    mx  = fmaxf(mx, __shfl_down(mx, 32)); mx = fmaxf(mx, __shfl_down(mx, 16));
    if (lane < 16) {
      sredS [cl][wm] = s;
      sredS2[cl][wm] = s2;
      sredM [cl][wm] = mx;
    }
  }
  __syncthreads();
  if (t < BN) {
    const int o = o0 + t;
    float s  = sredS [t][0] + sredS [t][1];
    float s2 = sredS2[t][0] + sredS2[t][1];
    if (out) {
      spart[(o << 8) + blockIdx.x] = make_float2(s, s2);
    } else {
      float mx = fmaxf(sredM[t][0], sredM[t][1]);
      atomicAdd(&stat_acc[o], s);
      atomicAdd(&stat_acc[C_out + o], s2);
      atomicMax(&max_acc[b * C_out + o], encf(mx));
    }
  }
}

// ---------- MFMA KAN layer v7w: WIDE-N wave (64 pts x 128 cols, acc[4][8]) ----------
// For L5 only (hottest dispatch). Per K-step: same 4 T-loads + 36 poly VALU ops as
// the narrow kernel, but 8 B-frags and 32 MFMAs -> MFMA:VALU ~2:1 and A-redundancy
// across n-waves halves. Block = 4 waves (2m x 2n) covering 128 pts x 256 cols.
// Budget: 128 acc + ~100 stage/addr ~ 230 regs -> launch_bounds(256,2), depth 2.
__global__ __launch_bounds__(256, 2) void kan_mfma7w(
    const unsigned* __restrict__ T16,
    const half8* __restrict__ wh,      // conv_w16 layout with BN=256
    const float* __restrict__ bias,
    float*       __restrict__ out,
    float2*      __restrict__ spart,
    float*       __restrict__ stat_acc,
    unsigned*    __restrict__ max_acc,
    int C_in, int C_out)
{
  constexpr int BN = 256;
  const int nslot = C_in >> 1;
  __shared__ float sredS[BN][2], sredS2[BN][2], sredM[BN][2];

  const int t    = threadIdx.x;
  const int lane = t & 63;
  const int col  = lane & 15;
  const int quad = lane >> 4;
  const int wv   = t >> 6;
  const int wm   = wv & 1;
  const int wn   = wv >> 1;          // 0..1, covers 128 cols each
  const int b    = blockIdx.x >> 3;
  const int n0   = (blockIdx.x & 7) << 7;
  const int o0   = blockIdx.y << 8;

  f32x4 acc[4][8];
#pragma unroll
  for (int i = 0; i < 4; ++i)
#pragma unroll
    for (int j = 0; j < 8; ++j)
#pragma unroll
      for (int k = 0; k < 4; ++k) acc[i][j][k] = 0.0f;

  const unsigned* Tp = T16 + (((size_t)(b * nslot + quad)) << 10) + n0 + (wm << 6) + col;
  const half8*    Bp = wh + (size_t)blockIdx.y * nslot * BN + (size_t)quad * BN + (wn << 7) + col;

  const half2v c375  = {(_Float16)3.75f,  (_Float16)3.75f};
  const half2v cm075 = {(_Float16)-0.75f, (_Float16)-0.75f};
  const half2v c70   = {(_Float16)7.0f,   (_Float16)7.0f};
  const half2v cm30  = {(_Float16)-3.0f,  (_Float16)-3.0f};

#define KLOADW(TTR, BFR, J) do {                                           \
    const unsigned* tp_ = Tp + (((size_t)(unsigned)(J)) << 12);            \
    const half8*    bp_ = Bp + (size_t)(unsigned)(J) * (BN << 2);          \
    TTR[0] = tp_[0];  TTR[1] = tp_[16];                                    \
    TTR[2] = tp_[32]; TTR[3] = tp_[48];                                    \
    BFR[0] = bp_[0];  BFR[1] = bp_[16];                                    \
    BFR[2] = bp_[32]; BFR[3] = bp_[48];                                    \
    BFR[4] = bp_[64]; BFR[5] = bp_[80];                                    \
    BFR[6] = bp_[96]; BFR[7] = bp_[112];                                   \
  } while (0)

#define KSTEPW(TTR, BFR) do {                                              \
    half8 af_[4];                                                          \
    _Pragma("unroll")                                                      \
    for (int fm_ = 0; fm_ < 4; ++fm_) {                                    \
      half2v tt = __builtin_bit_cast(half2v, TTR[fm_]);                    \
      half2v t2 = tt * tt;                                                 \
      half2v q1 = tt + tt;                                                 \
      half2v q2 = t2 * c375 + cm075;                                       \
      half2v q3 = tt * (t2 * c70 + cm30);                                  \
      half8 h;                                                             \
      h[0] = (_Float16)1.0f; h[1] = q1[0]; h[2] = q2[0]; h[3] = q3[0];     \
      h[4] = (_Float16)1.0f; h[5] = q1[1]; h[6] = q2[1]; h[7] = q3[1];     \
      af_[fm_] = h;                                                        \
    }                                                                      \
    _Pragma("unroll")                                                      \
    for (int fm_ = 0; fm_ < 4; ++fm_) {                                    \
      _Pragma("unroll")                                                    \
      for (int fn_ = 0; fn_ < 8; ++fn_)                                    \
        acc[fm_][fn_] = __builtin_amdgcn_mfma_f32_16x16x32_f16(            \
            af_[fm_], BFR[fn_], acc[fm_][fn_], 0, 0, 0);                   \
    }                                                                      \
  } while (0)

  const int nIt = nslot >> 2;   // L5: 16
  unsigned ttA[4], ttB[4];
  half8    bfA[8], bfB[8];
  KLOADW(ttA, bfA, 0);
  KLOADW(ttB, bfB, 1);
  int it = 0;
  for (; it + 3 < nIt; it += 2) {
    KSTEPW(ttA, bfA); KLOADW(ttA, bfA, it + 2);
    KSTEPW(ttB, bfB); KLOADW(ttB, bfB, it + 3);
  }
  KSTEPW(ttA, bfA);
  KSTEPW(ttB, bfB);

#undef KLOADW
#undef KSTEPW

  const float inv64 = 0.015625f;
#pragma unroll
  for (int fn = 0; fn < 8; ++fn) {
    const int cl = (wn << 7) + (fn << 4) + col;
    const int o  = o0 + cl;
    const float bb = bias ? bias[b * C_out + o] : 0.0f;
    float s = 0.f, s2 = 0.f, mx = -3.4e38f;
#pragma unroll
    for (int fm = 0; fm < 4; ++fm) {
      float v0 = acc[fm][fn][0] * inv64 + bb;
      float v1 = acc[fm][fn][1] * inv64 + bb;
      float v2 = acc[fm][fn][2] * inv64 + bb;
      float v3 = acc[fm][fn][3] * inv64 + bb;
      if (out) {
        *(float4*)(out + (((size_t)(b * C_out + o)) << 10) + n0 + (wm << 6) + (fm << 4) + (quad << 2)) =
            make_float4(v0, v1, v2, v3);
      }
      s  += v0 + v1 + v2 + v3;
      s2 += v0 * v0 + v1 * v1 + v2 * v2 + v3 * v3;
      mx  = fmaxf(fmaxf(v0, v1), fmaxf(fmaxf(v2, v3), mx));
    }
    s  += __shfl_down(s, 32);  s  += __shfl_down(s, 16);
    s2 += __shfl_down(s2, 32); s2 += __shfl_down(s2, 16);
    mx  = fmaxf(mx, __shfl_down(mx, 32)); mx = fmaxf(mx, __shfl_down(mx, 16));
    if (lane < 16) {
      sredS [cl][wm] = s;
      sredS2[cl][wm] = s2;
      sredM [cl][wm] = mx;
    }
  }
  __syncthreads();
  {
    const int o = o0 + t;
    float s  = sredS [t][0] + sredS [t][1];
    float s2 = sredS2[t][0] + sredS2[t][1];
    if (out) {
      spart[(o << 8) + blockIdx.x] = make_float2(s, s2);
    } else {
      float mx = fmaxf(sredM[t][0], sredM[t][1]);
      atomicAdd(&stat_acc[o], s);
      atomicAdd(&stat_acc[C_out + o], s2);
      atomicMax(&max_acc[b * C_out + o], encf(mx));
    }
  }
}

// ---------- fp32 KAN layer (L1 only: C_in=2) ----------
template<int BM, int BN>
__global__ __launch_bounds__(256) void kan_gemm(
    const float*  __restrict__ in, const float2* __restrict__ stats,
    const float*  __restrict__ w, float* __restrict__ out,
    float2* __restrict__ spart, int C_in, int C_out)
{
  static_assert(BM * BN == 256 * 64, "8x8-per-thread tile requires BM*BN == 16384");
  constexpr int TM = BM / 8;
  constexpr int AE = 8 * BM / 256;
  constexpr int BE = 8 * BN / 256;
  __shared__ __align__(16) float As[32][BM];
  __shared__ __align__(16) float Bs[32][BN];

  const int t  = threadIdx.x;
  const int tpb = NPTS / BM;
  const int b  = blockIdx.x / tpb;
  const int n0 = (blockIdx.x % tpb) * BM;
  const int o0 = blockIdx.y * BN;
  const int tm = t % TM;
  const int to = t / TM;

  float acc[2][4][2][4];
#pragma unroll
  for (int a = 0; a < 2; ++a)
#pragma unroll
    for (int c = 0; c < 4; ++c)
#pragma unroll
      for (int d = 0; d < 2; ++d)
#pragma unroll
        for (int e = 0; e < 4; ++e) acc[a][c][d][e] = 0.0f;

  const int nch = (C_in + 7) >> 3;
  for (int ch = 0; ch < nch; ++ch) {
    const int i0 = ch << 3;
    __syncthreads();
#pragma unroll
    for (int r = 0; r < AE; ++r) {
      int e  = t + (r << 8);
      int il = e / BM, n = e % BM;
      int i  = i0 + il;
      float p0 = 0.f, p1 = 0.f, p2 = 0.f, p3 = 0.f;
      if (i < C_in) {
        float v = in[((size_t)(b * C_in + i) << 10) + n0 + n];
        if (stats) { float2 s = stats[i]; v = (v - s.x) * s.y; }
        jacobi4(fast_tanh(v), p0, p1, p2, p3);
      }
      As[(il << 2) + 0][n] = p0;
      As[(il << 2) + 1][n] = p1;
      As[(il << 2) + 2][n] = p2;
      As[(il << 2) + 3][n] = p3;
    }
#pragma unroll
    for (int r = 0; r < BE; ++r) {
      int e  = t + (r << 8);
      int il = e / BN, o = e % BN;
      int i  = i0 + il;
      float4 wv = make_float4(0.f, 0.f, 0.f, 0.f);
      if (i < C_in) wv = *(const float4*)(w + (((size_t)i * C_out + o0 + o) << 2));
      Bs[(il << 2) + 0][o] = wv.x;
      Bs[(il << 2) + 1][o] = wv.y;
      Bs[(il << 2) + 2][o] = wv.z;
      Bs[(il << 2) + 3][o] = wv.w;
    }
    __syncthreads();
#pragma unroll 8
    for (int k = 0; k < 32; ++k) {
      const float4 a0 = *(const float4*)&As[k][tm << 2];
      const float4 a1 = *(const float4*)&As[k][(BM / 2) + (tm << 2)];
      const float4 b0 = *(const float4*)&Bs[k][to << 2];
      const float4 b1 = *(const float4*)&Bs[k][(BN / 2) + (to << 2)];
      const float am[2][4] = {{a0.x, a0.y, a0.z, a0.w}, {a1.x, a1.y, a1.z, a1.w}};
      const float bo[2][4] = {{b0.x, b0.y, b0.z, b0.w}, {b1.x, b1.y, b1.z, b1.w}};
#pragma unroll
      for (int oh = 0; oh < 2; ++oh)
#pragma unroll
        for (int oj = 0; oj < 4; ++oj) {
          const float bv = bo[oh][oj];
#pragma unroll
          for (int mh = 0; mh < 2; ++mh)
#pragma unroll
            for (int mj = 0; mj < 4; ++mj)
              acc[oh][oj][mh][mj] = fmaf(bv, am[mh][mj], acc[oh][oj][mh][mj]);
        }
    }
  }

#pragma unroll
  for (int oh = 0; oh < 2; ++oh)
#pragma unroll
    for (int oj = 0; oj < 4; ++oj) {
      const int o = o0 + oh * (BN / 2) + (to << 2) + oj;
      float s = 0.f, s2 = 0.f;
#pragma unroll
      for (int mh = 0; mh < 2; ++mh) {
        float4 v = make_float4(acc[oh][oj][mh][0], acc[oh][oj][mh][1],
                               acc[oh][oj][mh][2], acc[oh][oj][mh][3]);
        *(float4*)(out + (((size_t)(b * C_out + o)) << 10) + n0 + mh * (BM / 2) + (tm << 2)) = v;
        s  += v.x + v.y + v.z + v.w;
        s2 += v.x * v.x + v.y * v.y + v.z * v.z + v.w * v.w;
      }
#pragma unroll
      for (int off = TM / 2; off > 0; off >>= 1) {
        s  += __shfl_down(s, off, TM);
        s2 += __shfl_down(s2, off, TM);
      }
      if (tm == 0) spart[(o << 8) + blockIdx.x] = make_float2(s, s2);
    }
}

// ---------- reduce per-block partials -> BN stats ----------
__global__ __launch_bounds__(256) void bn_finalize2(
    const float2* __restrict__ spart, float2* __restrict__ stats, int C, int nxb)
{
  int c = blockIdx.x, t = threadIdx.x;
  float s = 0.f, s2 = 0.f;
  if (t < nxb) { float2 p = spart[(c << 8) + t]; s = p.x; s2 = p.y; }
#pragma unroll
  for (int off = 32; off > 0; off >>= 1) {
    s  += __shfl_down(s, off);
    s2 += __shfl_down(s2, off);
  }
  __shared__ float rs[4], rs2[4];
  int wid = t >> 6;
  if ((t & 63) == 0) { rs[wid] = s; rs2[wid] = s2; }
  __syncthreads();
  if (t == 0) {
    s  = rs[0] + rs[1] + rs[2] + rs[3];
    s2 = rs2[0] + rs2[1] + rs2[2] + rs2[3];
    float m   = s * (1.0f / NTOT);
    float var = s2 * (1.0f / NTOT) - m * m;
    stats[c] = make_float2(m, rsqrtf(var + 1e-5f));
  }
}

// ---------- finalize layer-5 stats from atomic accumulators ----------
__global__ void bn_finalize(const float* __restrict__ stat_acc,
                            float2* __restrict__ stats, int C) {
  int c = blockIdx.x * 256 + threadIdx.x;
  if (c < C) {
    float m   = stat_acc[c] * (1.0f / NTOT);
    float var = stat_acc[C + c] * (1.0f / NTOT) - m * m;
    stats[c] = make_float2(m, rsqrtf(var + 1e-5f));
  }
}

// ---------- global-feature branch of layer 6, parallel ----------
__global__ __launch_bounds__(256) void pool_const6p(
    const unsigned* __restrict__ max_acc, const float2* __restrict__ stats5,
    const float* __restrict__ w6, float* __restrict__ cst)
{
  __shared__ __align__(16) float4 P[32][64];
  const int t  = threadIdx.x;
  const int ot = blockIdx.x;
  const int c0 = blockIdx.y << 6;
#pragma unroll
  for (int it = 0; it < 8; ++it) {
    int idx = t + (it << 8);
    int b = idx >> 6, cl = idx & 63;
    int c = c0 + cl;
    float mx = decf(max_acc[(b << 10) + c]);
    float2 s = stats5[c];
    float tt = fast_tanh((mx - s.x) * s.y);
    float p0, p1, p2, p3; jacobi4(tt, p0, p1, p2, p3);
    P[b][cl] = make_float4(p0, p1, p2, p3);
  }
  __syncthreads();
  const int oL = t & 63;
  const int bg = t >> 6;
  const int o  = (ot << 6) + oL;
  float acc[8];
#pragma unroll
  for (int i = 0; i < 8; ++i) acc[i] = 0.f;
  for (int cl = 0; cl < 64; ++cl) {
    const float4 wv = *(const float4*)(w6 + (((size_t)(64 + c0 + cl) * 512 + o) << 2));
#pragma unroll
    for (int bb = 0; bb < 8; ++bb) {
      float4 p = P[(bg << 3) + bb][cl];
      acc[bb] += p.x * wv.x + p.y * wv.y + p.z * wv.z + p.w * wv.w;
    }
  }
#pragma unroll
  for (int bb = 0; bb < 8; ++bb)
    atomicAdd(&cst[(((bg << 3) + bb) << 9) + o], acc[bb]);
}

// ---------- final layer: C_in=128 fp32 -> C_out=3 fp32 ----------
__global__ __launch_bounds__(256) void kan_final(
    const float* __restrict__ in, const float2* __restrict__ stats,
    const float* __restrict__ w, float* __restrict__ out)
{
  int g = blockIdx.x * 256 + threadIdx.x;
  int b = g >> 10, n = g & 1023;
  float a0 = 0.f, a1 = 0.f, a2 = 0.f;
  for (int i = 0; i < 128; ++i) {
    float v = in[((size_t)(b * 128 + i) << 10) + n];
    float2 s = stats[i];
    float p0, p1, p2, p3; jacobi4(fast_tanh((v - s.x) * s.y), p0, p1, p2, p3);
    const float4 w0 = *(const float4*)(w + ((i * 3 + 0) << 2));
    const float4 w1 = *(const float4*)(w + ((i * 3 + 1) << 2));
    const float4 w2 = *(const float4*)(w + ((i * 3 + 2) << 2));
    a0 += p0 * w0.x + p1 * w0.y + p2 * w0.z + p3 * w0.w;
    a1 += p0 * w1.x + p1 * w1.y + p2 * w1.z + p3 * w1.w;
    a2 += p0 * w2.x + p1 * w2.y + p2 * w2.z + p3 * w2.w;
  }
  out[((b * 3 + 0) << 10) + n] = a0;
  out[((b * 3 + 1) << 10) + n] = a1;
  out[((b * 3 + 2) << 10) + n] = a2;
}

// ---------- launch ----------
extern "C" void kernel_launch(void* const* d_in, const int* in_sizes, int n_in,
                              void* d_out, int out_size, void* d_ws, size_t ws_size,
                              hipStream_t stream) {
  const float* x   = (const float*)d_in[0];
  const float* w1  = (const float*)d_in[1];
  const float* w2  = (const float*)d_in[2];
  const float* w3  = (const float*)d_in[3];
  const float* w4  = (const float*)d_in[4];
  const float* w5  = (const float*)d_in[5];
  const float* w6  = (const float*)d_in[6];
  const float* w7  = (const float*)d_in[7];
  const float* w8  = (const float*)d_in[8];
  const float* w9  = (const float*)d_in[9];
  const float* w10 = (const float*)d_in[10];

  float* ws = (float*)d_ws;
  // misc region (floats)
  float*    stat_acc = ws + 0;                      // 2048
  unsigned* maxenc   = (unsigned*)(ws + 2048);      // 32768
  float*    cst6     = ws + 34816;                  // 16384 (zeroed)
  float2*   spart    = (float2*)(ws + 51200);       // 131072 float2 -> ends 313344
  float2*   stats1   = (float2*)(ws + 313344);
  float2*   stats2   = stats1 + 64;
  float2*   stats3   = stats2 + 64;
  float2*   stats4   = stats3 + 64;
  float2*   stats5   = stats4 + 128;
  float2*   stats6   = stats5 + 1024;
  float2*   stats7   = stats6 + 512;
  float2*   stats8   = stats7 + 256;
  float2*   stats9   = stats8 + 128;
  // fp16 weight pool (half8 units) @ float offset 318464 (same as proven fallback)
  half8*    whbase = (half8*)(ws + 318464);
  half8*    h2 = whbase + 0;        // 32*64    = 2048
  half8*    h3 = whbase + 2048;     // 2048
  half8*    h4 = whbase + 4096;     // 32*128   = 4096
  half8*    h5 = whbase + 8192;     // 64*1024  = 65536  (BN=256 tiling)
  half8*    h6 = whbase + 73728;    // 32*512   = 16384
  half8*    h7 = whbase + 90112;    // 256*256  = 65536
  half8*    h8 = whbase + 155648;   // 128*128  = 16384
  half8*    h9 = whbase + 172032;   // 64*128   = 8192  -> ends 720896 floats
  // data pool, liveness-aliased (units of MF = 1048576 floats; T16 sizes count u32 = float):
  //   T2:[0,1) act2..L6k | y1:[1,3) | T1:[3,4) | y2:[1,3) | y3:[1,3) | T3:[3,4)
  //   y4:[4,8) | T4:[1,3) | y6:[3,19) | T6:[19,27) | y7:[0,8) | T7:[8,12)
  //   y8:[0,4) | T8:[4,6) | y9:[12,16)      peak 27 MF -> total 28 MF = 112 MB
  const size_t MF = 1048576;
  float*    P   = ws + MF;
  unsigned* T2  = (unsigned*)(P + 0 * MF);
  float*    y1  = P + 1 * MF;
  unsigned* T1  = (unsigned*)(P + 3 * MF);
  float*    y2  = P + 1 * MF;
  float*    y3  = P + 1 * MF;
  unsigned* T3  = (unsigned*)(P + 3 * MF);
  float*    y4  = P + 4 * MF;
  unsigned* T4  = (unsigned*)(P + 1 * MF);
  float*    y6  = P + 3 * MF;
  unsigned* T6  = (unsigned*)(P + 19 * MF);
  float*    y7  = P + 0 * MF;
  unsigned* T7  = (unsigned*)(P + 8 * MF);
  float*    y8  = P + 0 * MF;
  unsigned* T8  = (unsigned*)(P + 4 * MF);
  float*    y9  = P + 12 * MF;

  dim3 blk(256);
  zero_ws<<<200, blk, 0, stream>>>((unsigned*)ws, 51200);
  // preconvert weights (x64, slot layout); h5 tiled at BN=256 for the wide kernel
  conv_w16<<<8,   blk, 0, stream>>>(w2, h2, 64, 64, 64);
  conv_w16<<<8,   blk, 0, stream>>>(w3, h3, 64, 64, 64);
  conv_w16<<<16,  blk, 0, stream>>>(w4, h4, 64, 128, 128);
  conv_w16<<<256, blk, 0, stream>>>(w5, h5, 128, 1024, 256);
  conv_w16<<<64,  blk, 0, stream>>>(w6, h6, 64, 512, 128);   // local rows 0..63
  conv_w16<<<256, blk, 0, stream>>>(w7, h7, 512, 256, 128);
  conv_w16<<<64,  blk, 0, stream>>>(w8, h8, 256, 128, 128);
  conv_w16<<<32,  blk, 0, stream>>>(w9, h9, 128, 128, 128);

  // L1: 2 -> 64 fp32
  kan_gemm<256, 64><<<dim3(128, 1), blk, 0, stream>>>(x, nullptr, w1, y1, spart, 2, 64);
  bn_finalize2<<<64, blk, 0, stream>>>(spart, stats1, 64, 128);
  act_tanh16<<<32 * 32, blk, 0, stream>>>(y1, stats1, T1, 64);
  // L2: 64 -> 64
  kan_mfma7<1, 2><<<dim3(256, 1), 128, 0, stream>>>(T1, h2, nullptr, y2, spart, nullptr, nullptr, 64, 64);
  bn_finalize2<<<64, blk, 0, stream>>>(spart, stats2, 64, 256);
  act_tanh16<<<32 * 32, blk, 0, stream>>>(y2, stats2, T2, 64);   // T2 kept for L6
  // L3: 64 -> 64
  kan_mfma7<1, 2><<<dim3(256, 1), 128, 0, stream>>>(T2, h3, nullptr, y3, spart, nullptr, nullptr, 64, 64);
  bn_finalize2<<<64, blk, 0, stream>>>(spart, stats3, 64, 256);
  act_tanh16<<<32 * 32, blk, 0, stream>>>(y3, stats3, T3, 64);
  // L4: 64 -> 128 (depth 2, R9 config)
  kan_mfma7<2, 2><<<dim3(256, 1), blk, 0, stream>>>(T3, h4, nullptr, y4, spart, nullptr, nullptr, 64, 128);
  bn_finalize2<<<128, blk, 0, stream>>>(spart, stats4, 128, 256);
  act_tanh16<<<32 * 64, blk, 0, stream>>>(y4, stats4, T4, 128);
  // L5: 128 -> 1024, fused stats + maxpool, WIDE-N waves (acc[4][8])
  kan_mfma7w<<<dim3(256, 4), blk, 0, stream>>>(T4, h5, nullptr, nullptr, nullptr, stat_acc, maxenc, 128, 1024);
  bn_finalize<<<4, blk, 0, stream>>>(stat_acc, stats5, 1024);
  // gf branch of layer 6
  pool_const6p<<<dim3(8, 16), blk, 0, stream>>>(maxenc, stats5, w6, cst6);
  // L6: 64 (local, T2) -> 512 + gf bias (depth 2, R9 config)
  kan_mfma7<2, 2><<<dim3(256, 4), blk, 0, stream>>>(T2, h6, cst6, y6, spart, nullptr, nullptr, 64, 512);
  bn_finalize2<<<512, blk, 0, stream>>>(spart, stats6, 512, 256);
  act_tanh16<<<32 * 256, blk, 0, stream>>>(y6, stats6, T6, 512);
  // L7: 512 -> 256 (depth 4, R9 config)
  kan_mfma7<2, 4><<<dim3(256, 2), blk, 0, stream>>>(T6, h7, nullptr, y7, spart, nullptr, nullptr, 512, 256);
  bn_finalize2<<<256, blk, 0, stream>>>(spart, stats7, 256, 256);
  act_tanh16<<<32 * 128, blk, 0, stream>>>(y7, stats7, T7, 256);
  // L8: 256 -> 128 (depth 4, R9 config)
  kan_mfma7<2, 4><<<dim3(256, 1), blk, 0, stream>>>(T7, h8, nullptr, y8, spart, nullptr, nullptr, 256, 128);
  bn_finalize2<<<128, blk, 0, stream>>>(spart, stats8, 128, 256);
  act_tanh16<<<32 * 64, blk, 0, stream>>>(y8, stats8, T8, 128);
  // L9: 128 -> 128 (depth 4, R9 config)
  kan_mfma7<2, 4><<<dim3(256, 1), blk, 0, stream>>>(T8, h9, nullptr, y9, spart, nullptr, nullptr, 128, 128);
  bn_finalize2<<<128, blk, 0, stream>>>(spart, stats9, 128, 256);
  // L10: 128 -> 3 (tanh+Jacobi inline, fp32)
  kan_final<<<128, blk, 0, stream>>>(y9, stats9, w10, (float*)d_out);
}

// Round 12
// 358.246 us; speedup vs baseline: 1.0546x; 1.0517x over previous
//
#include <hip/hip_runtime.h>

#define BATCH 32
#define NPTS  1024
#define NTOT  (BATCH * NPTS)   // 32768 points

typedef _Float16 half8  __attribute__((ext_vector_type(8)));
typedef _Float16 half2v __attribute__((ext_vector_type(2)));
typedef float    f32x4  __attribute__((ext_vector_type(4)));

// ---------- helpers ----------

__device__ __forceinline__ float fast_tanh(float x) {
  float ax = fabsf(x);
  float e  = __expf(-2.0f * ax);
  float t  = (1.0f - e) / (1.0f + e);
  return x < 0.0f ? -t : t;
}

// Jacobi polys for a=b=1, degree 3: p1=2t, p2=3.75t^2-0.75, p3=7t^3-3t
__device__ __forceinline__ void jacobi4(float t, float& p0, float& p1, float& p2, float& p3) {
  float t2 = t * t;
  p0 = 1.0f;
  p1 = 2.0f * t;
  p2 = 3.75f * t2 - 0.75f;
  p3 = t * (7.0f * t2 - 3.0f);
}

// monotone float<->uint encoding for atomicMax over signed floats
__device__ __forceinline__ unsigned encf(float f) {
  unsigned b = __float_as_uint(f);
  return b ^ ((unsigned)((int)b >> 31) | 0x80000000u);
}
__device__ __forceinline__ float decf(unsigned u) {
  unsigned b = (u & 0x80000000u) ? (u ^ 0x80000000u) : ~u;
  return __uint_as_float(b);
}

// ---------- zero workspace accumulators ----------
__global__ void zero_ws(unsigned* __restrict__ p, int n) {
  int i = blockIdx.x * 256 + threadIdx.x;
  if (i < n) p[i] = 0u;
}

// ---------- batched weight preconversion (slot layout, p0..p3), x64 scaled ----------
// All 8 layers in ONE dispatch; segment selected by blockIdx vs prefix table.
struct ConvArgs {
  const float* w[8];
  int cin[8];
  int cout[8];
  int bn[8];
  int blk0[8];    // prefix of block counts
  int whoff[8];   // offset into whbase, half8 units
};
__global__ __launch_bounds__(256) void conv_w16_all(ConvArgs a, half8* __restrict__ whb) {
  int bx = blockIdx.x;
  int i = 0;
#pragma unroll
  for (int k = 1; k < 8; ++k) if (bx >= a.blk0[k]) i = k;
  const int C_in = a.cin[i], C_out = a.cout[i], BN = a.bn[i];
  const float* __restrict__ w = a.w[i];
  half8* __restrict__ wh = whb + a.whoff[i];
  const int nslot = C_in >> 1;
  int tid = (bx - a.blk0[i]) * 256 + threadIdx.x;
  int oL = tid % BN;
  int r  = tid / BN;
  int s  = r % nslot;
  int ot = r / nslot;
  int ii = s << 1;
  int o  = ot * BN + oL;
  const float4 wa = *(const float4*)(w + (((size_t)ii * C_out + o) << 2));
  const float4 wb = *(const float4*)(w + (((size_t)(ii + 1) * C_out + o) << 2));
  half8 h;
  h[0] = (_Float16)(wa.x * 64.0f); h[1] = (_Float16)(wa.y * 64.0f);
  h[2] = (_Float16)(wa.z * 64.0f); h[3] = (_Float16)(wa.w * 64.0f);
  h[4] = (_Float16)(wb.x * 64.0f); h[5] = (_Float16)(wb.y * 64.0f);
  h[6] = (_Float16)(wb.z * 64.0f); h[7] = (_Float16)(wb.w * 64.0f);
  wh[tid] = h;
}

// ---------- FUSED stats + activation: spart -> (m,rsig) inline, y -> T16 ----------
// Replaces bn_finalize2 + act_tanh16 (one dispatch instead of two). Each block
// handles one (b, slot) = 2 channels x 1024 pts; redundantly reduces its two
// channels' spart rows (nxb entries, <= 4 KB L2 reads) with the SAME reduction
// order as bn_finalize2 (wave shfl + 4-wave LDS combine) -> bit-identical stats.
__global__ __launch_bounds__(256) void act_tanh16s(
    const float* __restrict__ y, const float2* __restrict__ spart,
    unsigned* __restrict__ T16, int C, int nxb)
{
  const int nslot = C >> 1;
  const int b  = blockIdx.x / nslot;
  const int s  = blockIdx.x - b * nslot;
  const int t  = threadIdx.x;
  const int c0 = s << 1;

  __shared__ float rs[2][4], rs2[2][4];
  __shared__ float2 stl[2];
  float a0s = 0.f, a0s2 = 0.f, a1s = 0.f, a1s2 = 0.f;
  if (t < nxb) {
    float2 p0 = spart[(c0 << 8) + t];
    float2 p1 = spart[((c0 + 1) << 8) + t];
    a0s = p0.x; a0s2 = p0.y;
    a1s = p1.x; a1s2 = p1.y;
  }
#pragma unroll
  for (int off = 32; off > 0; off >>= 1) {
    a0s  += __shfl_down(a0s, off);  a0s2 += __shfl_down(a0s2, off);
    a1s  += __shfl_down(a1s, off);  a1s2 += __shfl_down(a1s2, off);
  }
  int wid = t >> 6;
  if ((t & 63) == 0) { rs[0][wid] = a0s; rs2[0][wid] = a0s2; rs[1][wid] = a1s; rs2[1][wid] = a1s2; }
  __syncthreads();
  if (t < 2) {
    float su  = rs[t][0] + rs[t][1] + rs[t][2] + rs[t][3];
    float su2 = rs2[t][0] + rs2[t][1] + rs2[t][2] + rs2[t][3];
    float m   = su * (1.0f / NTOT);
    float var = su2 * (1.0f / NTOT) - m * m;
    stl[t] = make_float2(m, rsqrtf(var + 1e-5f));
  }
  __syncthreads();
  const float2 s0 = stl[0];
  const float2 s1 = stl[1];

  const int n = t << 2;
  const float* yp = y + (((size_t)(b * C + c0)) << 10) + n;
  float4 v0 = *(const float4*)yp;
  float4 v1 = *(const float4*)(yp + 1024);
  float q0[4] = {v0.x, v0.y, v0.z, v0.w};
  float q1[4] = {v1.x, v1.y, v1.z, v1.w};
  unsigned r[4];
#pragma unroll
  for (int k = 0; k < 4; ++k) {
    _Float16 h0 = (_Float16)fast_tanh((q0[k] - s0.x) * s0.y);
    _Float16 h1 = (_Float16)fast_tanh((q1[k] - s1.x) * s1.y);
    unsigned lo = (unsigned)__builtin_bit_cast(unsigned short, h0);
    unsigned hi = (unsigned)__builtin_bit_cast(unsigned short, h1);
    r[k] = lo | (hi << 16);
  }
  *(uint4*)(T16 + (((size_t)(b * nslot + s)) << 10) + n) = make_uint4(r[0], r[1], r[2], r[3]);
}

// ---------- MFMA KAN layer v7d: fp16 T input, packed-fp16 poly, DEPTH-buffer prefetch ----------
// R9-proven config: DEPTH=2 for TLP-rich layers (L2-L6), DEPTH=4 for grid-limited
// layers (L7/L8/L9). Runtime loop + named stage sets preserves prefetch distance.
template<int NBW, int DEPTH>
__global__ __launch_bounds__(NBW * 128, 2) void kan_mfma7(
    const unsigned* __restrict__ T16,  // (B, nslot, N) packed fp16 tanh pairs
    const half8* __restrict__ wh,
    const float* __restrict__ bias,    // (B, C_out) or nullptr
    float*       __restrict__ out,     // (B, C_out, N) fp32 or nullptr (L5 mode)
    float2*      __restrict__ spart,
    float*       __restrict__ stat_acc,
    unsigned*    __restrict__ max_acc,
    int C_in, int C_out)
{
  constexpr int BN = NBW * 64;
  const int nslot = C_in >> 1;
  __shared__ float sredS[BN][2], sredS2[BN][2], sredM[BN][2];

  const int t    = threadIdx.x;
  const int lane = t & 63;
  const int col  = lane & 15;
  const int quad = lane >> 4;
  const int wv   = t >> 6;
  const int wm   = wv & 1;
  const int wn   = wv >> 1;
  const int b    = blockIdx.x >> 3;
  const int n0   = (blockIdx.x & 7) << 7;
  const int o0   = blockIdx.y * BN;

  f32x4 acc[4][4];
#pragma unroll
  for (int i = 0; i < 4; ++i)
#pragma unroll
    for (int j = 0; j < 4; ++j)
#pragma unroll
      for (int k = 0; k < 4; ++k) acc[i][j][k] = 0.0f;

  const unsigned* Tp = T16 + (((size_t)(b * nslot + quad)) << 10) + n0 + (wm << 6) + col;
  const half8*    Bp = wh + (size_t)blockIdx.y * nslot * BN + (size_t)quad * BN + wn * 64 + col;

  const half2v c375  = {(_Float16)3.75f,  (_Float16)3.75f};
  const half2v cm075 = {(_Float16)-0.75f, (_Float16)-0.75f};
  const half2v c70   = {(_Float16)7.0f,   (_Float16)7.0f};
  const half2v cm30  = {(_Float16)-3.0f,  (_Float16)-3.0f};

#define KLOAD(TTR, BFR, J) do {                                            \
    const unsigned* tp_ = Tp + (((size_t)(unsigned)(J)) << 12);            \
    const half8*    bp_ = Bp + (size_t)(unsigned)(J) * (BN << 2);          \
    TTR[0] = tp_[0];  TTR[1] = tp_[16];                                    \
    TTR[2] = tp_[32]; TTR[3] = tp_[48];                                    \
    BFR[0] = bp_[0];  BFR[1] = bp_[16];                                    \
    BFR[2] = bp_[32]; BFR[3] = bp_[48];                                    \
  } while (0)

#define KSTEP(TTR, BFR) do {                                               \
    half8 af_[4];                                                          \
    _Pragma("unroll")                                                      \
    for (int fm_ = 0; fm_ < 4; ++fm_) {                                    \
      half2v tt = __builtin_bit_cast(half2v, TTR[fm_]);                    \
      half2v t2 = tt * tt;                                                 \
      half2v q1 = tt + tt;                                                 \
      half2v q2 = t2 * c375 + cm075;                                       \
      half2v q3 = tt * (t2 * c70 + cm30);                                  \
      half8 h;                                                             \
      h[0] = (_Float16)1.0f; h[1] = q1[0]; h[2] = q2[0]; h[3] = q3[0];     \
      h[4] = (_Float16)1.0f; h[5] = q1[1]; h[6] = q2[1]; h[7] = q3[1];     \
      af_[fm_] = h;                                                        \
    }                                                                      \
    _Pragma("unroll")                                                      \
    for (int fm_ = 0; fm_ < 4; ++fm_) {                                    \
      _Pragma("unroll")                                                    \
      for (int fn_ = 0; fn_ < 4; ++fn_)                                    \
        acc[fm_][fn_] = __builtin_amdgcn_mfma_f32_16x16x32_f16(            \
            af_[fm_], BFR[fn_], acc[fm_][fn_], 0, 0, 0);                   \
    }                                                                      \
  } while (0)

  const int nIt = nslot >> 2;   // 8 / 16 / 32 / 64 — all % 4 == 0
  if constexpr (DEPTH == 2) {
    unsigned ttA[4], ttB[4];
    half8    bfA[4], bfB[4];
    KLOAD(ttA, bfA, 0);
    KLOAD(ttB, bfB, 1);
    int it = 0;
    for (; it + 3 < nIt; it += 2) {
      KSTEP(ttA, bfA); KLOAD(ttA, bfA, it + 2);
      KSTEP(ttB, bfB); KLOAD(ttB, bfB, it + 3);
    }
    KSTEP(ttA, bfA);
    KSTEP(ttB, bfB);
  } else {
    unsigned ttA[4], ttB[4], ttC[4], ttD[4];
    half8    bfA[4], bfB[4], bfC[4], bfD[4];
    KLOAD(ttA, bfA, 0);
    KLOAD(ttB, bfB, 1);
    KLOAD(ttC, bfC, 2);
    KLOAD(ttD, bfD, 3);
    int it = 0;
    for (; it + 7 < nIt; it += 4) {
      KSTEP(ttA, bfA); KLOAD(ttA, bfA, it + 4);
      KSTEP(ttB, bfB); KLOAD(ttB, bfB, it + 5);
      KSTEP(ttC, bfC); KLOAD(ttC, bfC, it + 6);
      KSTEP(ttD, bfD); KLOAD(ttD, bfD, it + 7);
    }
    KSTEP(ttA, bfA);
    KSTEP(ttB, bfB);
    KSTEP(ttC, bfC);
    KSTEP(ttD, bfD);
  }

#undef KLOAD
#undef KSTEP

  const float inv64 = 0.015625f;
#pragma unroll
  for (int fn = 0; fn < 4; ++fn) {
    const int cl = (wn << 6) + (fn << 4) + col;
    const int o  = o0 + cl;
    const float bb = bias ? bias[b * C_out + o] : 0.0f;
    float s = 0.f, s2 = 0.f, mx = -3.4e38f;
#pragma unroll
    for (int fm = 0; fm < 4; ++fm) {
      float v0 = acc[fm][fn][0] * inv64 + bb;
      float v1 = acc[fm][fn][1] * inv64 + bb;
      float v2 = acc[fm][fn][2] * inv64 + bb;
      float v3 = acc[fm][fn][3] * inv64 + bb;
      if (out) {
        *(float4*)(out + (((size_t)(b * C_out + o)) << 10) + n0 + (wm << 6) + (fm << 4) + (quad << 2)) =
            make_float4(v0, v1, v2, v3);
      }
      s  += v0 + v1 + v2 + v3;
      s2 += v0 * v0 + v1 * v1 + v2 * v2 + v3 * v3;
      mx  = fmaxf(fmaxf(v0, v1), fmaxf(fmaxf(v2, v3), mx));
    }
    s  += __shfl_down(s, 32);  s  += __shfl_down(s, 16);
    s2 += __shfl_down(s2, 32); s2 += __shfl_down(s2, 16);
    mx  = fmaxf(mx, __shfl_down(mx, 32)); mx = fmaxf(mx, __shfl_down(mx, 16));
    if (lane < 16) {
      sredS [cl][wm] = s;
      sredS2[cl][wm] = s2;
      sredM [cl][wm] = mx;
    }
  }
  __syncthreads();
  if (t < BN) {
    const int o = o0 + t;
    float s  = sredS [t][0] + sredS [t][1];
    float s2 = sredS2[t][0] + sredS2[t][1];
    if (out) {
      spart[(o << 8) + blockIdx.x] = make_float2(s, s2);
    } else {
      float mx = fmaxf(sredM[t][0], sredM[t][1]);
      atomicAdd(&stat_acc[o], s);
      atomicAdd(&stat_acc[C_out + o], s2);
      atomicMax(&max_acc[b * C_out + o], encf(mx));
    }
  }
}

// ---------- fp32 KAN layer (L1 only: C_in=2) ----------
template<int BM, int BN>
__global__ __launch_bounds__(256) void kan_gemm(
    const float*  __restrict__ in, const float2* __restrict__ stats,
    const float*  __restrict__ w, float* __restrict__ out,
    float2* __restrict__ spart, int C_in, int C_out)
{
  static_assert(BM * BN == 256 * 64, "8x8-per-thread tile requires BM*BN == 16384");
  constexpr int TM = BM / 8;
  constexpr int AE = 8 * BM / 256;
  constexpr int BE = 8 * BN / 256;
  __shared__ __align__(16) float As[32][BM];
  __shared__ __align__(16) float Bs[32][BN];

  const int t  = threadIdx.x;
  const int tpb = NPTS / BM;
  const int b  = blockIdx.x / tpb;
  const int n0 = (blockIdx.x % tpb) * BM;
  const int o0 = blockIdx.y * BN;
  const int tm = t % TM;
  const int to = t / TM;

  float acc[2][4][2][4];
#pragma unroll
  for (int a = 0; a < 2; ++a)
#pragma unroll
    for (int c = 0; c < 4; ++c)
#pragma unroll
      for (int d = 0; d < 2; ++d)
#pragma unroll
        for (int e = 0; e < 4; ++e) acc[a][c][d][e] = 0.0f;

  const int nch = (C_in + 7) >> 3;
  for (int ch = 0; ch < nch; ++ch) {
    const int i0 = ch << 3;
    __syncthreads();
#pragma unroll
    for (int r = 0; r < AE; ++r) {
      int e  = t + (r << 8);
      int il = e / BM, n = e % BM;
      int i  = i0 + il;
      float p0 = 0.f, p1 = 0.f, p2 = 0.f, p3 = 0.f;
      if (i < C_in) {
        float v = in[((size_t)(b * C_in + i) << 10) + n0 + n];
        if (stats) { float2 s = stats[i]; v = (v - s.x) * s.y; }
        jacobi4(fast_tanh(v), p0, p1, p2, p3);
      }
      As[(il << 2) + 0][n] = p0;
      As[(il << 2) + 1][n] = p1;
      As[(il << 2) + 2][n] = p2;
      As[(il << 2) + 3][n] = p3;
    }
#pragma unroll
    for (int r = 0; r < BE; ++r) {
      int e  = t + (r << 8);
      int il = e / BN, o = e % BN;
      int i  = i0 + il;
      float4 wv = make_float4(0.f, 0.f, 0.f, 0.f);
      if (i < C_in) wv = *(const float4*)(w + (((size_t)i * C_out + o0 + o) << 2));
      Bs[(il << 2) + 0][o] = wv.x;
      Bs[(il << 2) + 1][o] = wv.y;
      Bs[(il << 2) + 2][o] = wv.z;
      Bs[(il << 2) + 3][o] = wv.w;
    }
    __syncthreads();
#pragma unroll 8
    for (int k = 0; k < 32; ++k) {
      const float4 a0 = *(const float4*)&As[k][tm << 2];
      const float4 a1 = *(const float4*)&As[k][(BM / 2) + (tm << 2)];
      const float4 b0 = *(const float4*)&Bs[k][to << 2];
      const float4 b1 = *(const float4*)&Bs[k][(BN / 2) + (to << 2)];
      const float am[2][4] = {{a0.x, a0.y, a0.z, a0.w}, {a1.x, a1.y, a1.z, a1.w}};
      const float bo[2][4] = {{b0.x, b0.y, b0.z, b0.w}, {b1.x, b1.y, b1.z, b1.w}};
#pragma unroll
      for (int oh = 0; oh < 2; ++oh)
#pragma unroll
        for (int oj = 0; oj < 4; ++oj) {
          const float bv = bo[oh][oj];
#pragma unroll
          for (int mh = 0; mh < 2; ++mh)
#pragma unroll
            for (int mj = 0; mj < 4; ++mj)
              acc[oh][oj][mh][mj] = fmaf(bv, am[mh][mj], acc[oh][oj][mh][mj]);
        }
    }
  }

#pragma unroll
  for (int oh = 0; oh < 2; ++oh)
#pragma unroll
    for (int oj = 0; oj < 4; ++oj) {
      const int o = o0 + oh * (BN / 2) + (to << 2) + oj;
      float s = 0.f, s2 = 0.f;
#pragma unroll
      for (int mh = 0; mh < 2; ++mh) {
        float4 v = make_float4(acc[oh][oj][mh][0], acc[oh][oj][mh][1],
                               acc[oh][oj][mh][2], acc[oh][oj][mh][3]);
        *(float4*)(out + (((size_t)(b * C_out + o)) << 10) + n0 + mh * (BM / 2) + (tm << 2)) = v;
        s  += v.x + v.y + v.z + v.w;
        s2 += v.x * v.x + v.y * v.y + v.z * v.z + v.w * v.w;
      }
#pragma unroll
      for (int off = TM / 2; off > 0; off >>= 1) {
        s  += __shfl_down(s, off, TM);
        s2 += __shfl_down(s2, off, TM);
      }
      if (tm == 0) spart[(o << 8) + blockIdx.x] = make_float2(s, s2);
    }
}

// ---------- reduce per-block partials -> BN stats (L9 only; kan_final needs stats) ----------
__global__ __launch_bounds__(256) void bn_finalize2(
    const float2* __restrict__ spart, float2* __restrict__ stats, int C, int nxb)
{
  int c = blockIdx.x, t = threadIdx.x;
  float s = 0.f, s2 = 0.f;
  if (t < nxb) { float2 p = spart[(c << 8) + t]; s = p.x; s2 = p.y; }
#pragma unroll
  for (int off = 32; off > 0; off >>= 1) {
    s  += __shfl_down(s, off);
    s2 += __shfl_down(s2, off);
  }
  __shared__ float rs[4], rs2[4];
  int wid = t >> 6;
  if ((t & 63) == 0) { rs[wid] = s; rs2[wid] = s2; }
  __syncthreads();
  if (t == 0) {
    s  = rs[0] + rs[1] + rs[2] + rs[3];
    s2 = rs2[0] + rs2[1] + rs2[2] + rs2[3];
    float m   = s * (1.0f / NTOT);
    float var = s2 * (1.0f / NTOT) - m * m;
    stats[c] = make_float2(m, rsqrtf(var + 1e-5f));
  }
}

// ---------- finalize layer-5 stats from atomic accumulators ----------
__global__ void bn_finalize(const float* __restrict__ stat_acc,
                            float2* __restrict__ stats, int C) {
  int c = blockIdx.x * 256 + threadIdx.x;
  if (c < C) {
    float m   = stat_acc[c] * (1.0f / NTOT);
    float var = stat_acc[C + c] * (1.0f / NTOT) - m * m;
    stats[c] = make_float2(m, rsqrtf(var + 1e-5f));
  }
}

// ---------- global-feature branch of layer 6, parallel ----------
__global__ __launch_bounds__(256) void pool_const6p(
    const unsigned* __restrict__ max_acc, const float2* __restrict__ stats5,
    const float* __restrict__ w6, float* __restrict__ cst)
{
  __shared__ __align__(16) float4 P[32][64];
  const int t  = threadIdx.x;
  const int ot = blockIdx.x;
  const int c0 = blockIdx.y << 6;
#pragma unroll
  for (int it = 0; it < 8; ++it) {
    int idx = t + (it << 8);
    int b = idx >> 6, cl = idx & 63;
    int c = c0 + cl;
    float mx = decf(max_acc[(b << 10) + c]);
    float2 s = stats5[c];
    float tt = fast_tanh((mx - s.x) * s.y);
    float p0, p1, p2, p3; jacobi4(tt, p0, p1, p2, p3);
    P[b][cl] = make_float4(p0, p1, p2, p3);
  }
  __syncthreads();
  const int oL = t & 63;
  const int bg = t >> 6;
  const int o  = (ot << 6) + oL;
  float acc[8];
#pragma unroll
  for (int i = 0; i < 8; ++i) acc[i] = 0.f;
  for (int cl = 0; cl < 64; ++cl) {
    const float4 wv = *(const float4*)(w6 + (((size_t)(64 + c0 + cl) * 512 + o) << 2));
#pragma unroll
    for (int bb = 0; bb < 8; ++bb) {
      float4 p = P[(bg << 3) + bb][cl];
      acc[bb] += p.x * wv.x + p.y * wv.y + p.z * wv.z + p.w * wv.w;
    }
  }
#pragma unroll
  for (int bb = 0; bb < 8; ++bb)
    atomicAdd(&cst[(((bg << 3) + bb) << 9) + o], acc[bb]);
}

// ---------- final layer: C_in=128 fp32 -> C_out=3 fp32 ----------
__global__ __launch_bounds__(256) void kan_final(
    const float* __restrict__ in, const float2* __restrict__ stats,
    const float* __restrict__ w, float* __restrict__ out)
{
  int g = blockIdx.x * 256 + threadIdx.x;
  int b = g >> 10, n = g & 1023;
  float a0 = 0.f, a1 = 0.f, a2 = 0.f;
  for (int i = 0; i < 128; ++i) {
    float v = in[((size_t)(b * 128 + i) << 10) + n];
    float2 s = stats[i];
    float p0, p1, p2, p3; jacobi4(fast_tanh((v - s.x) * s.y), p0, p1, p2, p3);
    const float4 w0 = *(const float4*)(w + ((i * 3 + 0) << 2));
    const float4 w1 = *(const float4*)(w + ((i * 3 + 1) << 2));
    const float4 w2 = *(const float4*)(w + ((i * 3 + 2) << 2));
    a0 += p0 * w0.x + p1 * w0.y + p2 * w0.z + p3 * w0.w;
    a1 += p0 * w1.x + p1 * w1.y + p2 * w1.z + p3 * w1.w;
    a2 += p0 * w2.x + p1 * w2.y + p2 * w2.z + p3 * w2.w;
  }
  out[((b * 3 + 0) << 10) + n] = a0;
  out[((b * 3 + 1) << 10) + n] = a1;
  out[((b * 3 + 2) << 10) + n] = a2;
}

// ---------- launch ----------
extern "C" void kernel_launch(void* const* d_in, const int* in_sizes, int n_in,
                              void* d_out, int out_size, void* d_ws, size_t ws_size,
                              hipStream_t stream) {
  const float* x   = (const float*)d_in[0];
  const float* w1  = (const float*)d_in[1];
  const float* w2  = (const float*)d_in[2];
  const float* w3  = (const float*)d_in[3];
  const float* w4  = (const float*)d_in[4];
  const float* w5  = (const float*)d_in[5];
  const float* w6  = (const float*)d_in[6];
  const float* w7  = (const float*)d_in[7];
  const float* w8  = (const float*)d_in[8];
  const float* w9  = (const float*)d_in[9];
  const float* w10 = (const float*)d_in[10];

  float* ws = (float*)d_ws;
  // misc region (floats)
  float*    stat_acc = ws + 0;                      // 2048
  unsigned* maxenc   = (unsigned*)(ws + 2048);      // 32768
  float*    cst6     = ws + 34816;                  // 16384 (zeroed)
  float2*   spart    = (float2*)(ws + 51200);       // 131072 float2 -> ends 313344
  float2*   stats5   = (float2*)(ws + 313344);      // 1024
  float2*   stats9   = stats5 + 1024;               // 128
  // fp16 weight pool (half8 units) @ float offset 318464
  half8*    whbase = (half8*)(ws + 318464);
  half8*    h2 = whbase + 0;        // 32*64    = 2048
  half8*    h3 = whbase + 2048;     // 2048
  half8*    h4 = whbase + 4096;     // 32*128   = 4096
  half8*    h5 = whbase + 8192;     // 64*1024  = 65536
  half8*    h6 = whbase + 73728;    // 32*512   = 16384
  half8*    h7 = whbase + 90112;    // 256*256  = 65536
  half8*    h8 = whbase + 155648;   // 128*128  = 16384
  half8*    h9 = whbase + 172032;   // 64*128   = 8192  -> ends 720896 floats
  // data pool, liveness-aliased (units of MF = 1048576 floats; T16 sizes count u32 = float)
  const size_t MF = 1048576;
  float*    P   = ws + MF;
  unsigned* T2  = (unsigned*)(P + 0 * MF);
  float*    y1  = P + 1 * MF;
  unsigned* T1  = (unsigned*)(P + 3 * MF);
  float*    y2  = P + 1 * MF;
  float*    y3  = P + 1 * MF;
  unsigned* T3  = (unsigned*)(P + 3 * MF);
  float*    y4  = P + 4 * MF;
  unsigned* T4  = (unsigned*)(P + 1 * MF);
  float*    y6  = P + 3 * MF;
  unsigned* T6  = (unsigned*)(P + 19 * MF);
  float*    y7  = P + 0 * MF;
  unsigned* T7  = (unsigned*)(P + 8 * MF);
  float*    y8  = P + 0 * MF;
  unsigned* T8  = (unsigned*)(P + 4 * MF);
  float*    y9  = P + 12 * MF;

  dim3 blk(256);
  zero_ws<<<200, blk, 0, stream>>>((unsigned*)ws, 51200);

  // batched weight preconversion: one dispatch for all 8 layers
  ConvArgs ca;
  ca.w[0] = w2;  ca.w[1] = w3;  ca.w[2] = w4;  ca.w[3] = w5;
  ca.w[4] = w6;  ca.w[5] = w7;  ca.w[6] = w8;  ca.w[7] = w9;
  const int cins[8]  = {64, 64, 64, 128, 64, 512, 256, 128};
  const int couts[8] = {64, 64, 128, 1024, 512, 256, 128, 128};
  const int bns[8]   = {64, 64, 128, 128, 128, 128, 128, 128};
  const int whof[8]  = {0, 2048, 4096, 8192, 73728, 90112, 155648, 172032};
  int acc_blk = 0;
  for (int i = 0; i < 8; ++i) {
    ca.cin[i] = cins[i]; ca.cout[i] = couts[i]; ca.bn[i] = bns[i]; ca.whoff[i] = whof[i];
    ca.blk0[i] = acc_blk;
    acc_blk += (cins[i] >> 1) * couts[i] / 256;   // nslot*C_out elements / 256 threads
  }
  conv_w16_all<<<acc_blk, blk, 0, stream>>>(ca, whbase);

  // L1: 2 -> 64 fp32 (spart nxb = 128)
  kan_gemm<256, 64><<<dim3(128, 1), blk, 0, stream>>>(x, nullptr, w1, y1, spart, 2, 64);
  act_tanh16s<<<32 * 32, blk, 0, stream>>>(y1, spart, T1, 64, 128);
  // L2: 64 -> 64
  kan_mfma7<1, 2><<<dim3(256, 1), 128, 0, stream>>>(T1, h2, nullptr, y2, spart, nullptr, nullptr, 64, 64);
  act_tanh16s<<<32 * 32, blk, 0, stream>>>(y2, spart, T2, 64, 256);   // T2 kept for L6
  // L3: 64 -> 64
  kan_mfma7<1, 2><<<dim3(256, 1), 128, 0, stream>>>(T2, h3, nullptr, y3, spart, nullptr, nullptr, 64, 64);
  act_tanh16s<<<32 * 32, blk, 0, stream>>>(y3, spart, T3, 64, 256);
  // L4: 64 -> 128 (depth 2)
  kan_mfma7<2, 2><<<dim3(256, 1), blk, 0, stream>>>(T3, h4, nullptr, y4, spart, nullptr, nullptr, 64, 128);
  act_tanh16s<<<32 * 64, blk, 0, stream>>>(y4, spart, T4, 128, 256);
  // L5: 128 -> 1024, fused stats + maxpool, no materialization (depth 2)
  kan_mfma7<2, 2><<<dim3(256, 8), blk, 0, stream>>>(T4, h5, nullptr, nullptr, nullptr, stat_acc, maxenc, 128, 1024);
  bn_finalize<<<4, blk, 0, stream>>>(stat_acc, stats5, 1024);
  // gf branch of layer 6
  pool_const6p<<<dim3(8, 16), blk, 0, stream>>>(maxenc, stats5, w6, cst6);
  // L6: 64 (local, T2) -> 512 + gf bias (depth 2)
  kan_mfma7<2, 2><<<dim3(256, 4), blk, 0, stream>>>(T2, h6, cst6, y6, spart, nullptr, nullptr, 64, 512);
  act_tanh16s<<<32 * 256, blk, 0, stream>>>(y6, spart, T6, 512, 256);
  // L7: 512 -> 256 (depth 4)
  kan_mfma7<2, 4><<<dim3(256, 2), blk, 0, stream>>>(T6, h7, nullptr, y7, spart, nullptr, nullptr, 512, 256);
  act_tanh16s<<<32 * 128, blk, 0, stream>>>(y7, spart, T7, 256, 256);
  // L8: 256 -> 128 (depth 4)
  kan_mfma7<2, 4><<<dim3(256, 1), blk, 0, stream>>>(T7, h8, nullptr, y8, spart, nullptr, nullptr, 256, 128);
  act_tanh16s<<<32 * 64, blk, 0, stream>>>(y8, spart, T8, 128, 256);
  // L9: 128 -> 128 (depth 4); stats9 still needed by kan_final
  kan_mfma7<2, 4><<<dim3(256, 1), blk, 0, stream>>>(T8, h9, nullptr, y9, spart, nullptr, nullptr, 128, 128);
  bn_finalize2<<<128, blk, 0, stream>>>(spart, stats9, 128, 256);
  // L10: 128 -> 3 (tanh+Jacobi inline, fp32)
  kan_final<<<128, blk, 0, stream>>>(y9, stats9, w10, (float*)d_out);
}

// Round 14
// 357.521 us; speedup vs baseline: 1.0568x; 1.0020x over previous
//
#include <hip/hip_runtime.h>

#define BATCH 32
#define NPTS  1024
#define NTOT  (BATCH * NPTS)   // 32768 points

typedef _Float16 half8  __attribute__((ext_vector_type(8)));
typedef _Float16 half2v __attribute__((ext_vector_type(2)));
typedef float    f32x4  __attribute__((ext_vector_type(4)));

// ---------- helpers ----------

__device__ __forceinline__ float fast_tanh(float x) {
  float ax = fabsf(x);
  float e  = __expf(-2.0f * ax);
  float t  = (1.0f - e) / (1.0f + e);
  return x < 0.0f ? -t : t;
}

// Jacobi polys for a=b=1, degree 3: p1=2t, p2=3.75t^2-0.75, p3=7t^3-3t
__device__ __forceinline__ void jacobi4(float t, float& p0, float& p1, float& p2, float& p3) {
  float t2 = t * t;
  p0 = 1.0f;
  p1 = 2.0f * t;
  p2 = 3.75f * t2 - 0.75f;
  p3 = t * (7.0f * t2 - 3.0f);
}

// monotone float<->uint encoding for atomicMax over signed floats
__device__ __forceinline__ unsigned encf(float f) {
  unsigned b = __float_as_uint(f);
  return b ^ ((unsigned)((int)b >> 31) | 0x80000000u);
}
__device__ __forceinline__ float decf(unsigned u) {
  unsigned b = (u & 0x80000000u) ? (u ^ 0x80000000u) : ~u;
  return __uint_as_float(b);
}

// ---------- zero workspace accumulators ----------
__global__ void zero_ws(unsigned* __restrict__ p, int n) {
  int i = blockIdx.x * 256 + threadIdx.x;
  if (i < n) p[i] = 0u;
}

// ---------- batched weight preconversion: JACOBI basis, pair-interleaved k ----------
// k-order within a quad's 8 slots: {c0,c1} x {p0,p1,p2,p3}:
//   h[0]=w0(c0) h[1]=w0(c1) h[2]=w1(c0) h[3]=w1(c1)
//   h[4]=w2(c0) h[5]=w2(c1) h[6]=w3(c0) h[7]=w3(c1)    (all x64)
// A-frag dwords are then packed half2 {c0,c1} pairs: dword0=(1,1) const,
// dword1=q1-pair, dword2=q2-pair, dword3=q3-pair -> zero pack/perm ops.
// Same fp16 weight values & products as the proven R12 kernel (absmax 0.00427);
// only the MFMA k-slot order differs (fp32 accumulate).
struct ConvArgs {
  const float* w[8];
  int cin[8];
  int cout[8];
  int bn[8];
  int blk0[8];    // prefix of block counts
  int whoff[8];   // offset into whbase, half8 units
};
__global__ __launch_bounds__(256) void conv_w16_all(ConvArgs a, half8* __restrict__ whb) {
  int bx = blockIdx.x;
  int i = 0;
#pragma unroll
  for (int k = 1; k < 8; ++k) if (bx >= a.blk0[k]) i = k;
  const int C_in = a.cin[i], C_out = a.cout[i], BN = a.bn[i];
  const float* __restrict__ w = a.w[i];
  half8* __restrict__ wh = whb + a.whoff[i];
  const int nslot = C_in >> 1;
  int tid = (bx - a.blk0[i]) * 256 + threadIdx.x;
  int oL = tid % BN;
  int r  = tid / BN;
  int s  = r % nslot;
  int ot = r / nslot;
  int ii = s << 1;
  int o  = ot * BN + oL;
  const float4 wa = *(const float4*)(w + (((size_t)ii * C_out + o) << 2));
  const float4 wb = *(const float4*)(w + (((size_t)(ii + 1) * C_out + o) << 2));
  half8 h;
  h[0] = (_Float16)(wa.x * 64.0f); h[1] = (_Float16)(wb.x * 64.0f);
  h[2] = (_Float16)(wa.y * 64.0f); h[3] = (_Float16)(wb.y * 64.0f);
  h[4] = (_Float16)(wa.z * 64.0f); h[5] = (_Float16)(wb.z * 64.0f);
  h[6] = (_Float16)(wa.w * 64.0f); h[7] = (_Float16)(wb.w * 64.0f);
  wh[tid] = h;
}

// ---------- FUSED stats + activation: spart -> (m,rsig) inline, y -> T16 ----------
__global__ __launch_bounds__(256) void act_tanh16s(
    const float* __restrict__ y, const float2* __restrict__ spart,
    unsigned* __restrict__ T16, int C, int nxb)
{
  const int nslot = C >> 1;
  const int b  = blockIdx.x / nslot;
  const int s  = blockIdx.x - b * nslot;
  const int t  = threadIdx.x;
  const int c0 = s << 1;

  __shared__ float rs[2][4], rs2[2][4];
  __shared__ float2 stl[2];
  float a0s = 0.f, a0s2 = 0.f, a1s = 0.f, a1s2 = 0.f;
  if (t < nxb) {
    float2 p0 = spart[(c0 << 8) + t];
    float2 p1 = spart[((c0 + 1) << 8) + t];
    a0s = p0.x; a0s2 = p0.y;
    a1s = p1.x; a1s2 = p1.y;
  }
#pragma unroll
  for (int off = 32; off > 0; off >>= 1) {
    a0s  += __shfl_down(a0s, off);  a0s2 += __shfl_down(a0s2, off);
    a1s  += __shfl_down(a1s, off);  a1s2 += __shfl_down(a1s2, off);
  }
  int wid = t >> 6;
  if ((t & 63) == 0) { rs[0][wid] = a0s; rs2[0][wid] = a0s2; rs[1][wid] = a1s; rs2[1][wid] = a1s2; }
  __syncthreads();
  if (t < 2) {
    float su  = rs[t][0] + rs[t][1] + rs[t][2] + rs[t][3];
    float su2 = rs2[t][0] + rs2[t][1] + rs2[t][2] + rs2[t][3];
    float m   = su * (1.0f / NTOT);
    float var = su2 * (1.0f / NTOT) - m * m;
    stl[t] = make_float2(m, rsqrtf(var + 1e-5f));
  }
  __syncthreads();
  const float2 s0 = stl[0];
  const float2 s1 = stl[1];

  const int n = t << 2;
  const float* yp = y + (((size_t)(b * C + c0)) << 10) + n;
  float4 v0 = *(const float4*)yp;
  float4 v1 = *(const float4*)(yp + 1024);
  float q0[4] = {v0.x, v0.y, v0.z, v0.w};
  float q1[4] = {v1.x, v1.y, v1.z, v1.w};
  unsigned r[4];
#pragma unroll
  for (int k = 0; k < 4; ++k) {
    _Float16 h0 = (_Float16)fast_tanh((q0[k] - s0.x) * s0.y);
    _Float16 h1 = (_Float16)fast_tanh((q1[k] - s1.x) * s1.y);
    unsigned lo = (unsigned)__builtin_bit_cast(unsigned short, h0);
    unsigned hi = (unsigned)__builtin_bit_cast(unsigned short, h1);
    r[k] = lo | (hi << 16);
  }
  *(uint4*)(T16 + (((size_t)(b * nslot + s)) << 10) + n) = make_uint4(r[0], r[1], r[2], r[3]);
}

// ---------- MFMA KAN layer v10: Jacobi basis, pair-interleaved k, zero-pack A ----------
// A-frag dwords: {(1,1), q1-pair, q2-pair, q3-pair} — 5 pk ops, no pack/perm.
// R9-proven schedule: DEPTH=2 for TLP-rich layers (L2-L6), DEPTH=4 for
// grid-limited layers (L7/L8/L9); runtime loop + named stage sets.
template<int NBW, int DEPTH>
__global__ __launch_bounds__(NBW * 128, 2) void kan_mfma7(
    const unsigned* __restrict__ T16,  // (B, nslot, N) packed fp16 tanh pairs
    const half8* __restrict__ wh,
    const float* __restrict__ bias,    // (B, C_out) or nullptr
    float*       __restrict__ out,     // (B, C_out, N) fp32 or nullptr (L5 mode)
    float2*      __restrict__ spart,
    float*       __restrict__ stat_acc,
    unsigned*    __restrict__ max_acc,
    int C_in, int C_out)
{
  constexpr int BN = NBW * 64;
  const int nslot = C_in >> 1;
  __shared__ float sredS[BN][2], sredS2[BN][2], sredM[BN][2];

  const int t    = threadIdx.x;
  const int lane = t & 63;
  const int col  = lane & 15;
  const int quad = lane >> 4;
  const int wv   = t >> 6;
  const int wm   = wv & 1;
  const int wn   = wv >> 1;
  const int b    = blockIdx.x >> 3;
  const int n0   = (blockIdx.x & 7) << 7;
  const int o0   = blockIdx.y * BN;

  f32x4 acc[4][4];
#pragma unroll
  for (int i = 0; i < 4; ++i)
#pragma unroll
    for (int j = 0; j < 4; ++j)
#pragma unroll
      for (int k = 0; k < 4; ++k) acc[i][j][k] = 0.0f;

  const unsigned* Tp = T16 + (((size_t)(b * nslot + quad)) << 10) + n0 + (wm << 6) + col;
  const half8*    Bp = wh + (size_t)blockIdx.y * nslot * BN + (size_t)quad * BN + wn * 64 + col;

  const half2v c375  = {(_Float16)3.75f,  (_Float16)3.75f};
  const half2v cm075 = {(_Float16)-0.75f, (_Float16)-0.75f};
  const half2v c70   = {(_Float16)7.0f,   (_Float16)7.0f};
  const half2v cm30  = {(_Float16)-3.0f,  (_Float16)-3.0f};

#define KLOAD(TTR, BFR, J) do {                                            \
    const unsigned* tp_ = Tp + (((size_t)(unsigned)(J)) << 12);            \
    const half8*    bp_ = Bp + (size_t)(unsigned)(J) * (BN << 2);          \
    TTR[0] = tp_[0];  TTR[1] = tp_[16];                                    \
    TTR[2] = tp_[32]; TTR[3] = tp_[48];                                    \
    BFR[0] = bp_[0];  BFR[1] = bp_[16];                                    \
    BFR[2] = bp_[32]; BFR[3] = bp_[48];                                    \
  } while (0)

#define KSTEP(TTR, BFR) do {                                               \
    half8 af_[4];                                                          \
    _Pragma("unroll")                                                      \
    for (int fm_ = 0; fm_ < 4; ++fm_) {                                    \
      half2v tt = __builtin_bit_cast(half2v, TTR[fm_]);                    \
      half2v t2 = tt * tt;                                                 \
      half2v q1 = tt + tt;                                                 \
      half2v q2 = t2 * c375 + cm075;                                       \
      half2v q3 = tt * (t2 * c70 + cm30);                                  \
      af_[fm_] = __builtin_bit_cast(half8, make_uint4(                     \
          0x3C003C00u,                                                     \
          __builtin_bit_cast(unsigned, q1),                                \
          __builtin_bit_cast(unsigned, q2),                                \
          __builtin_bit_cast(unsigned, q3)));                              \
    }                                                                      \
    _Pragma("unroll")                                                      \
    for (int fm_ = 0; fm_ < 4; ++fm_) {                                    \
      _Pragma("unroll")                                                    \
      for (int fn_ = 0; fn_ < 4; ++fn_)                                    \
        acc[fm_][fn_] = __builtin_amdgcn_mfma_f32_16x16x32_f16(            \
            af_[fm_], BFR[fn_], acc[fm_][fn_], 0, 0, 0);                   \
    }                                                                      \
  } while (0)

  const int nIt = nslot >> 2;   // 8 / 16 / 32 / 64 — all % 4 == 0
  if constexpr (DEPTH == 2) {
    unsigned ttA[4], ttB[4];
    half8    bfA[4], bfB[4];
    KLOAD(ttA, bfA, 0);
    KLOAD(ttB, bfB, 1);
    int it = 0;
    for (; it + 3 < nIt; it += 2) {
      KSTEP(ttA, bfA); KLOAD(ttA, bfA, it + 2);
      KSTEP(ttB, bfB); KLOAD(ttB, bfB, it + 3);
    }
    KSTEP(ttA, bfA);
    KSTEP(ttB, bfB);
  } else {
    unsigned ttA[4], ttB[4], ttC[4], ttD[4];
    half8    bfA[4], bfB[4], bfC[4], bfD[4];
    KLOAD(ttA, bfA, 0);
    KLOAD(ttB, bfB, 1);
    KLOAD(ttC, bfC, 2);
    KLOAD(ttD, bfD, 3);
    int it = 0;
    for (; it + 7 < nIt; it += 4) {
      KSTEP(ttA, bfA); KLOAD(ttA, bfA, it + 4);
      KSTEP(ttB, bfB); KLOAD(ttB, bfB, it + 5);
      KSTEP(ttC, bfC); KLOAD(ttC, bfC, it + 6);
      KSTEP(ttD, bfD); KLOAD(ttD, bfD, it + 7);
    }
    KSTEP(ttA, bfA);
    KSTEP(ttB, bfB);
    KSTEP(ttC, bfC);
    KSTEP(ttD, bfD);
  }

#undef KLOAD
#undef KSTEP

  const float inv64 = 0.015625f;
#pragma unroll
  for (int fn = 0; fn < 4; ++fn) {
    const int cl = (wn << 6) + (fn << 4) + col;
    const int o  = o0 + cl;
    const float bb = bias ? bias[b * C_out + o] : 0.0f;
    float s = 0.f, s2 = 0.f, mx = -3.4e38f;
#pragma unroll
    for (int fm = 0; fm < 4; ++fm) {
      float v0 = acc[fm][fn][0] * inv64 + bb;
      float v1 = acc[fm][fn][1] * inv64 + bb;
      float v2 = acc[fm][fn][2] * inv64 + bb;
      float v3 = acc[fm][fn][3] * inv64 + bb;
      if (out) {
        *(float4*)(out + (((size_t)(b * C_out + o)) << 10) + n0 + (wm << 6) + (fm << 4) + (quad << 2)) =
            make_float4(v0, v1, v2, v3);
      }
      s  += v0 + v1 + v2 + v3;
      s2 += v0 * v0 + v1 * v1 + v2 * v2 + v3 * v3;
      mx  = fmaxf(fmaxf(v0, v1), fmaxf(fmaxf(v2, v3), mx));
    }
    s  += __shfl_down(s, 32);  s  += __shfl_down(s, 16);
    s2 += __shfl_down(s2, 32); s2 += __shfl_down(s2, 16);
    mx  = fmaxf(mx, __shfl_down(mx, 32)); mx = fmaxf(mx, __shfl_down(mx, 16));
    if (lane < 16) {
      sredS [cl][wm] = s;
      sredS2[cl][wm] = s2;
      sredM [cl][wm] = mx;
    }
  }
  __syncthreads();
  if (t < BN) {
    const int o = o0 + t;
    float s  = sredS [t][0] + sredS [t][1];
    float s2 = sredS2[t][0] + sredS2[t][1];
    if (out) {
      spart[(o << 8) + blockIdx.x] = make_float2(s, s2);
    } else {
      float mx = fmaxf(sredM[t][0], sredM[t][1]);
      atomicAdd(&stat_acc[o], s);
      atomicAdd(&stat_acc[C_out + o], s2);
      atomicMax(&max_acc[b * C_out + o], encf(mx));
    }
  }
}

// ---------- fp32 KAN layer (L1 only: C_in=2) ----------
template<int BM, int BN>
__global__ __launch_bounds__(256) void kan_gemm(
    const float*  __restrict__ in, const float2* __restrict__ stats,
    const float*  __restrict__ w, float* __restrict__ out,
    float2* __restrict__ spart, int C_in, int C_out)
{
  static_assert(BM * BN == 256 * 64, "8x8-per-thread tile requires BM*BN == 16384");
  constexpr int TM = BM / 8;
  constexpr int AE = 8 * BM / 256;
  constexpr int BE = 8 * BN / 256;
  __shared__ __align__(16) float As[32][BM];
  __shared__ __align__(16) float Bs[32][BN];

  const int t  = threadIdx.x;
  const int tpb = NPTS / BM;
  const int b  = blockIdx.x / tpb;
  const int n0 = (blockIdx.x % tpb) * BM;
  const int o0 = blockIdx.y * BN;
  const int tm = t % TM;
  const int to = t / TM;

  float acc[2][4][2][4];
#pragma unroll
  for (int a = 0; a < 2; ++a)
#pragma unroll
    for (int c = 0; c < 4; ++c)
#pragma unroll
      for (int d = 0; d < 2; ++d)
#pragma unroll
        for (int e = 0; e < 4; ++e) acc[a][c][d][e] = 0.0f;

  const int nch = (C_in + 7) >> 3;
  for (int ch = 0; ch < nch; ++ch) {
    const int i0 = ch << 3;
    __syncthreads();
#pragma unroll
    for (int r = 0; r < AE; ++r) {
      int e  = t + (r << 8);
      int il = e / BM, n = e % BM;
      int i  = i0 + il;
      float p0 = 0.f, p1 = 0.f, p2 = 0.f, p3 = 0.f;
      if (i < C_in) {
        float v = in[((size_t)(b * C_in + i) << 10) + n0 + n];
        if (stats) { float2 s = stats[i]; v = (v - s.x) * s.y; }
        jacobi4(fast_tanh(v), p0, p1, p2, p3);
      }
      As[(il << 2) + 0][n] = p0;
      As[(il << 2) + 1][n] = p1;
      As[(il << 2) + 2][n] = p2;
      As[(il << 2) + 3][n] = p3;
    }
#pragma unroll
    for (int r = 0; r < BE; ++r) {
      int e  = t + (r << 8);
      int il = e / BN, o = e % BN;
      int i  = i0 + il;
      float4 wv = make_float4(0.f, 0.f, 0.f, 0.f);
      if (i < C_in) wv = *(const float4*)(w + (((size_t)i * C_out + o0 + o) << 2));
      Bs[(il << 2) + 0][o] = wv.x;
      Bs[(il << 2) + 1][o] = wv.y;
      Bs[(il << 2) + 2][o] = wv.z;
      Bs[(il << 2) + 3][o] = wv.w;
    }
    __syncthreads();
#pragma unroll 8
    for (int k = 0; k < 32; ++k) {
      const float4 a0 = *(const float4*)&As[k][tm << 2];
      const float4 a1 = *(const float4*)&As[k][(BM / 2) + (tm << 2)];
      const float4 b0 = *(const float4*)&Bs[k][to << 2];
      const float4 b1 = *(const float4*)&Bs[k][(BN / 2) + (to << 2)];
      const float am[2][4] = {{a0.x, a0.y, a0.z, a0.w}, {a1.x, a1.y, a1.z, a1.w}};
      const float bo[2][4] = {{b0.x, b0.y, b0.z, b0.w}, {b1.x, b1.y, b1.z, b1.w}};
#pragma unroll
      for (int oh = 0; oh < 2; ++oh)
#pragma unroll
        for (int oj = 0; oj < 4; ++oj) {
          const float bv = bo[oh][oj];
#pragma unroll
          for (int mh = 0; mh < 2; ++mh)
#pragma unroll
            for (int mj = 0; mj < 4; ++mj)
              acc[oh][oj][mh][mj] = fmaf(bv, am[mh][mj], acc[oh][oj][mh][mj]);
        }
    }
  }

#pragma unroll
  for (int oh = 0; oh < 2; ++oh)
#pragma unroll
    for (int oj = 0; oj < 4; ++oj) {
      const int o = o0 + oh * (BN / 2) + (to << 2) + oj;
      float s = 0.f, s2 = 0.f;
#pragma unroll
      for (int mh = 0; mh < 2; ++mh) {
        float4 v = make_float4(acc[oh][oj][mh][0], acc[oh][oj][mh][1],
                               acc[oh][oj][mh][2], acc[oh][oj][mh][3]);
        *(float4*)(out + (((size_t)(b * C_out + o)) << 10) + n0 + mh * (BM / 2) + (tm << 2)) = v;
        s  += v.x + v.y + v.z + v.w;
        s2 += v.x * v.x + v.y * v.y + v.z * v.z + v.w * v.w;
      }
#pragma unroll
      for (int off = TM / 2; off > 0; off >>= 1) {
        s  += __shfl_down(s, off, TM);
        s2 += __shfl_down(s2, off, TM);
      }
      if (tm == 0) spart[(o << 8) + blockIdx.x] = make_float2(s, s2);
    }
}

// ---------- reduce per-block partials -> BN stats (L9 only; kan_final needs stats) ----------
__global__ __launch_bounds__(256) void bn_finalize2(
    const float2* __restrict__ spart, float2* __restrict__ stats, int C, int nxb)
{
  int c = blockIdx.x, t = threadIdx.x;
  float s = 0.f, s2 = 0.f;
  if (t < nxb) { float2 p = spart[(c << 8) + t]; s = p.x; s2 = p.y; }
#pragma unroll
  for (int off = 32; off > 0; off >>= 1) {
    s  += __shfl_down(s, off);
    s2 += __shfl_down(s2, off);
  }
  __shared__ float rs[4], rs2[4];
  int wid = t >> 6;
  if ((t & 63) == 0) { rs[wid] = s; rs2[wid] = s2; }
  __syncthreads();
  if (t == 0) {
    s  = rs[0] + rs[1] + rs[2] + rs[3];
    s2 = rs2[0] + rs2[1] + rs2[2] + rs2[3];
    float m   = s * (1.0f / NTOT);
    float var = s2 * (1.0f / NTOT) - m * m;
    stats[c] = make_float2(m, rsqrtf(var + 1e-5f));
  }
}

// ---------- finalize layer-5 stats from atomic accumulators ----------
__global__ void bn_finalize(const float* __restrict__ stat_acc,
                            float2* __restrict__ stats, int C) {
  int c = blockIdx.x * 256 + threadIdx.x;
  if (c < C) {
    float m   = stat_acc[c] * (1.0f / NTOT);
    float var = stat_acc[C + c] * (1.0f / NTOT) - m * m;
    stats[c] = make_float2(m, rsqrtf(var + 1e-5f));
  }
}

// ---------- global-feature branch of layer 6, parallel ----------
__global__ __launch_bounds__(256) void pool_const6p(
    const unsigned* __restrict__ max_acc, const float2* __restrict__ stats5,
    const float* __restrict__ w6, float* __restrict__ cst)
{
  __shared__ __align__(16) float4 P[32][64];
  const int t  = threadIdx.x;
  const int ot = blockIdx.x;
  const int c0 = blockIdx.y << 6;
#pragma unroll
  for (int it = 0; it < 8; ++it) {
    int idx = t + (it << 8);
    int b = idx >> 6, cl = idx & 63;
    int c = c0 + cl;
    float mx = decf(max_acc[(b << 10) + c]);
    float2 s = stats5[c];
    float tt = fast_tanh((mx - s.x) * s.y);
    float p0, p1, p2, p3; jacobi4(tt, p0, p1, p2, p3);
    P[b][cl] = make_float4(p0, p1, p2, p3);
  }
  __syncthreads();
  const int oL = t & 63;
  const int bg = t >> 6;
  const int o  = (ot << 6) + oL;
  float acc[8];
#pragma unroll
  for (int i = 0; i < 8; ++i) acc[i] = 0.f;
  for (int cl = 0; cl < 64; ++cl) {
    const float4 wv = *(const float4*)(w6 + (((size_t)(64 + c0 + cl) * 512 + o) << 2));
#pragma unroll
    for (int bb = 0; bb < 8; ++bb) {
      float4 p = P[(bg << 3) + bb][cl];
      acc[bb] += p.x * wv.x + p.y * wv.y + p.z * wv.z + p.w * wv.w;
    }
  }
#pragma unroll
  for (int bb = 0; bb < 8; ++bb)
    atomicAdd(&cst[(((bg << 3) + bb) << 9) + o], acc[bb]);
}

// ---------- final layer: C_in=128 fp32 -> C_out=3 fp32 ----------
__global__ __launch_bounds__(256) void kan_final(
    const float* __restrict__ in, const float2* __restrict__ stats,
    const float* __restrict__ w, float* __restrict__ out)
{
  int g = blockIdx.x * 256 + threadIdx.x;
  int b = g >> 10, n = g & 1023;
  float a0 = 0.f, a1 = 0.f, a2 = 0.f;
  for (int i = 0; i < 128; ++i) {
    float v = in[((size_t)(b * 128 + i) << 10) + n];
    float2 s = stats[i];
    float p0, p1, p2, p3; jacobi4(fast_tanh((v - s.x) * s.y), p0, p1, p2, p3);
    const float4 w0 = *(const float4*)(w + ((i * 3 + 0) << 2));
    const float4 w1 = *(const float4*)(w + ((i * 3 + 1) << 2));
    const float4 w2 = *(const float4*)(w + ((i * 3 + 2) << 2));
    a0 += p0 * w0.x + p1 * w0.y + p2 * w0.z + p3 * w0.w;
    a1 += p0 * w1.x + p1 * w1.y + p2 * w1.z + p3 * w1.w;
    a2 += p0 * w2.x + p1 * w2.y + p2 * w2.z + p3 * w2.w;
  }
  out[((b * 3 + 0) << 10) + n] = a0;
  out[((b * 3 + 1) << 10) + n] = a1;
  out[((b * 3 + 2) << 10) + n] = a2;
}

// ---------- launch ----------
extern "C" void kernel_launch(void* const* d_in, const int* in_sizes, int n_in,
                              void* d_out, int out_size, void* d_ws, size_t ws_size,
                              hipStream_t stream) {
  const float* x   = (const float*)d_in[0];
  const float* w1  = (const float*)d_in[1];
  const float* w2  = (const float*)d_in[2];
  const float* w3  = (const float*)d_in[3];
  const float* w4  = (const float*)d_in[4];
  const float* w5  = (const float*)d_in[5];
  const float* w6  = (const float*)d_in[6];
  const float* w7  = (const float*)d_in[7];
  const float* w8  = (const float*)d_in[8];
  const float* w9  = (const float*)d_in[9];
  const float* w10 = (const float*)d_in[10];

  float* ws = (float*)d_ws;
  // misc region (floats)
  float*    stat_acc = ws + 0;                      // 2048
  unsigned* maxenc   = (unsigned*)(ws + 2048);      // 32768
  float*    cst6     = ws + 34816;                  // 16384 (zeroed)
  float2*   spart    = (float2*)(ws + 51200);       // 131072 float2 -> ends 313344
  float2*   stats5   = (float2*)(ws + 313344);      // 1024
  float2*   stats9   = stats5 + 1024;               // 128
  // fp16 weight pool (half8 units) @ float offset 318464
  half8*    whbase = (half8*)(ws + 318464);
  half8*    h2 = whbase + 0;        // 32*64    = 2048
  half8*    h3 = whbase + 2048;     // 2048
  half8*    h4 = whbase + 4096;     // 32*128   = 4096
  half8*    h5 = whbase + 8192;     // 64*1024  = 65536
  half8*    h6 = whbase + 73728;    // 32*512   = 16384
  half8*    h7 = whbase + 90112;    // 256*256  = 65536
  half8*    h8 = whbase + 155648;   // 128*128  = 16384
  half8*    h9 = whbase + 172032;   // 64*128   = 8192  -> ends 720896 floats
  // data pool, liveness-aliased (units of MF = 1048576 floats; T16 sizes count u32 = float)
  const size_t MF = 1048576;
  float*    P   = ws + MF;
  unsigned* T2  = (unsigned*)(P + 0 * MF);
  float*    y1  = P + 1 * MF;
  unsigned* T1  = (unsigned*)(P + 3 * MF);
  float*    y2  = P + 1 * MF;
  float*    y3  = P + 1 * MF;
  unsigned* T3  = (unsigned*)(P + 3 * MF);
  float*    y4  = P + 4 * MF;
  unsigned* T4  = (unsigned*)(P + 1 * MF);
  float*    y6  = P + 3 * MF;
  unsigned* T6  = (unsigned*)(P + 19 * MF);
  float*    y7  = P + 0 * MF;
  unsigned* T7  = (unsigned*)(P + 8 * MF);
  float*    y8  = P + 0 * MF;
  unsigned* T8  = (unsigned*)(P + 4 * MF);
  float*    y9  = P + 12 * MF;

  dim3 blk(256);
  zero_ws<<<200, blk, 0, stream>>>((unsigned*)ws, 51200);

  // batched weight preconversion: one dispatch for all 8 layers (pair-interleave)
  ConvArgs ca;
  ca.w[0] = w2;  ca.w[1] = w3;  ca.w[2] = w4;  ca.w[3] = w5;
  ca.w[4] = w6;  ca.w[5] = w7;  ca.w[6] = w8;  ca.w[7] = w9;
  const int cins[8]  = {64, 64, 64, 128, 64, 512, 256, 128};
  const int couts[8] = {64, 64, 128, 1024, 512, 256, 128, 128};
  const int bns[8]   = {64, 64, 128, 128, 128, 128, 128, 128};
  const int whof[8]  = {0, 2048, 4096, 8192, 73728, 90112, 155648, 172032};
  int acc_blk = 0;
  for (int i = 0; i < 8; ++i) {
    ca.cin[i] = cins[i]; ca.cout[i] = couts[i]; ca.bn[i] = bns[i]; ca.whoff[i] = whof[i];
    ca.blk0[i] = acc_blk;
    acc_blk += (cins[i] >> 1) * couts[i] / 256;   // nslot*C_out elements / 256 threads
  }
  conv_w16_all<<<acc_blk, blk, 0, stream>>>(ca, whbase);

  // L1: 2 -> 64 fp32 (spart nxb = 128)
  kan_gemm<256, 64><<<dim3(128, 1), blk, 0, stream>>>(x, nullptr, w1, y1, spart, 2, 64);
  act_tanh16s<<<32 * 32, blk, 0, stream>>>(y1, spart, T1, 64, 128);
  // L2: 64 -> 64
  kan_mfma7<1, 2><<<dim3(256, 1), 128, 0, stream>>>(T1, h2, nullptr, y2, spart, nullptr, nullptr, 64, 64);
  act_tanh16s<<<32 * 32, blk, 0, stream>>>(y2, spart, T2, 64, 256);   // T2 kept for L6
  // L3: 64 -> 64
  kan_mfma7<1, 2><<<dim3(256, 1), 128, 0, stream>>>(T2, h3, nullptr, y3, spart, nullptr, nullptr, 64, 64);
  act_tanh16s<<<32 * 32, blk, 0, stream>>>(y3, spart, T3, 64, 256);
  // L4: 64 -> 128 (depth 2)
  kan_mfma7<2, 2><<<dim3(256, 1), blk, 0, stream>>>(T3, h4, nullptr, y4, spart, nullptr, nullptr, 64, 128);
  act_tanh16s<<<32 * 64, blk, 0, stream>>>(y4, spart, T4, 128, 256);
  // L5: 128 -> 1024, fused stats + maxpool, no materialization (depth 2)
  kan_mfma7<2, 2><<<dim3(256, 8), blk, 0, stream>>>(T4, h5, nullptr, nullptr, nullptr, stat_acc, maxenc, 128, 1024);
  bn_finalize<<<4, blk, 0, stream>>>(stat_acc, stats5, 1024);
  // gf branch of layer 6
  pool_const6p<<<dim3(8, 16), blk, 0, stream>>>(maxenc, stats5, w6, cst6);
  // L6: 64 (local, T2) -> 512 + gf bias (depth 2)
  kan_mfma7<2, 2><<<dim3(256, 4), blk, 0, stream>>>(T2, h6, cst6, y6, spart, nullptr, nullptr, 64, 512);
  act_tanh16s<<<32 * 256, blk, 0, stream>>>(y6, spart, T6, 512, 256);
  // L7: 512 -> 256 (depth 4)
  kan_mfma7<2, 4><<<dim3(256, 2), blk, 0, stream>>>(T6, h7, nullptr, y7, spart, nullptr, nullptr, 512, 256);
  act_tanh16s<<<32 * 128, blk, 0, stream>>>(y7, spart, T7, 256, 256);
  // L8: 256 -> 128 (depth 4)
  kan_mfma7<2, 4><<<dim3(256, 1), blk, 0, stream>>>(T7, h8, nullptr, y8, spart, nullptr, nullptr, 256, 128);
  act_tanh16s<<<32 * 64, blk, 0, stream>>>(y8, spart, T8, 128, 256);
  // L9: 128 -> 128 (depth 4); stats9 still needed by kan_final
  kan_mfma7<2, 4><<<dim3(256, 1), blk, 0, stream>>>(T8, h9, nullptr, y9, spart, nullptr, nullptr, 128, 128);
  bn_finalize2<<<128, blk, 0, stream>>>(spart, stats9, 128, 256);
  // L10: 128 -> 3 (tanh+Jacobi inline, fp32)
  kan_final<<<128, blk, 0, stream>>>(y9, stats9, w10, (float*)d_out);
}

// Round 15
// 356.931 us; speedup vs baseline: 1.0585x; 1.0017x over previous
//
#include <hip/hip_runtime.h>

#define BATCH 32
#define NPTS  1024
#define NTOT  (BATCH * NPTS)   // 32768 points

typedef _Float16 half8  __attribute__((ext_vector_type(8)));
typedef _Float16 half2v __attribute__((ext_vector_type(2)));
typedef float    f32x4  __attribute__((ext_vector_type(4)));

// ---------- helpers ----------

__device__ __forceinline__ float fast_tanh(float x) {
  float ax = fabsf(x);
  float e  = __expf(-2.0f * ax);
  float t  = (1.0f - e) / (1.0f + e);
  return x < 0.0f ? -t : t;
}

// Jacobi polys for a=b=1, degree 3: p1=2t, p2=3.75t^2-0.75, p3=7t^3-3t
__device__ __forceinline__ void jacobi4(float t, float& p0, float& p1, float& p2, float& p3) {
  float t2 = t * t;
  p0 = 1.0f;
  p1 = 2.0f * t;
  p2 = 3.75f * t2 - 0.75f;
  p3 = t * (7.0f * t2 - 3.0f);
}

// monotone float<->uint encoding for atomicMax over signed floats
__device__ __forceinline__ unsigned encf(float f) {
  unsigned b = __float_as_uint(f);
  return b ^ ((unsigned)((int)b >> 31) | 0x80000000u);
}
__device__ __forceinline__ float decf(unsigned u) {
  unsigned b = (u & 0x80000000u) ? (u ^ 0x80000000u) : ~u;
  return __uint_as_float(b);
}

// ---------- zero workspace accumulators ----------
__global__ void zero_ws(unsigned* __restrict__ p, int n) {
  int i = blockIdx.x * 256 + threadIdx.x;
  if (i < n) p[i] = 0u;
}

// ---------- batched weight preconversion: JACOBI basis, pair-interleaved k ----------
// k-order within a quad's 8 slots: {c0,c1} x {p0,p1,p2,p3}:
//   h[0]=w0(c0) h[1]=w0(c1) h[2]=w1(c0) h[3]=w1(c1)
//   h[4]=w2(c0) h[5]=w2(c1) h[6]=w3(c0) h[7]=w3(c1)    (all x64)
// A-frag dwords are then packed half2 {c0,c1} pairs: dword0=(1,1) const,
// dword1=q1-pair, dword2=q2-pair, dword3=q3-pair -> zero pack/perm ops.
struct ConvArgs {
  const float* w[8];
  int cin[8];
  int cout[8];
  int bn[8];
  int blk0[8];    // prefix of block counts
  int whoff[8];   // offset into whbase, half8 units
};
__global__ __launch_bounds__(256) void conv_w16_all(ConvArgs a, half8* __restrict__ whb) {
  int bx = blockIdx.x;
  int i = 0;
#pragma unroll
  for (int k = 1; k < 8; ++k) if (bx >= a.blk0[k]) i = k;
  const int C_in = a.cin[i], C_out = a.cout[i], BN = a.bn[i];
  const float* __restrict__ w = a.w[i];
  half8* __restrict__ wh = whb + a.whoff[i];
  const int nslot = C_in >> 1;
  int tid = (bx - a.blk0[i]) * 256 + threadIdx.x;
  int oL = tid % BN;
  int r  = tid / BN;
  int s  = r % nslot;
  int ot = r / nslot;
  int ii = s << 1;
  int o  = ot * BN + oL;
  const float4 wa = *(const float4*)(w + (((size_t)ii * C_out + o) << 2));
  const float4 wb = *(const float4*)(w + (((size_t)(ii + 1) * C_out + o) << 2));
  half8 h;
  h[0] = (_Float16)(wa.x * 64.0f); h[1] = (_Float16)(wb.x * 64.0f);
  h[2] = (_Float16)(wa.y * 64.0f); h[3] = (_Float16)(wb.y * 64.0f);
  h[4] = (_Float16)(wa.z * 64.0f); h[5] = (_Float16)(wb.z * 64.0f);
  h[6] = (_Float16)(wa.w * 64.0f); h[7] = (_Float16)(wb.w * 64.0f);
  wh[tid] = h;
}

// ---------- FUSED stats + activation: spart -> (m,rsig) inline, y -> T16 ----------
__global__ __launch_bounds__(256) void act_tanh16s(
    const float* __restrict__ y, const float2* __restrict__ spart,
    unsigned* __restrict__ T16, int C, int nxb)
{
  const int nslot = C >> 1;
  const int b  = blockIdx.x / nslot;
  const int s  = blockIdx.x - b * nslot;
  const int t  = threadIdx.x;
  const int c0 = s << 1;

  __shared__ float rs[2][4], rs2[2][4];
  __shared__ float2 stl[2];
  float a0s = 0.f, a0s2 = 0.f, a1s = 0.f, a1s2 = 0.f;
  if (t < nxb) {
    float2 p0 = spart[(c0 << 8) + t];
    float2 p1 = spart[((c0 + 1) << 8) + t];
    a0s = p0.x; a0s2 = p0.y;
    a1s = p1.x; a1s2 = p1.y;
  }
#pragma unroll
  for (int off = 32; off > 0; off >>= 1) {
    a0s  += __shfl_down(a0s, off);  a0s2 += __shfl_down(a0s2, off);
    a1s  += __shfl_down(a1s, off);  a1s2 += __shfl_down(a1s2, off);
  }
  int wid = t >> 6;
  if ((t & 63) == 0) { rs[0][wid] = a0s; rs2[0][wid] = a0s2; rs[1][wid] = a1s; rs2[1][wid] = a1s2; }
  __syncthreads();
  if (t < 2) {
    float su  = rs[t][0] + rs[t][1] + rs[t][2] + rs[t][3];
    float su2 = rs2[t][0] + rs2[t][1] + rs2[t][2] + rs2[t][3];
    float m   = su * (1.0f / NTOT);
    float var = su2 * (1.0f / NTOT) - m * m;
    stl[t] = make_float2(m, rsqrtf(var + 1e-5f));
  }
  __syncthreads();
  const float2 s0 = stl[0];
  const float2 s1 = stl[1];

  const int n = t << 2;
  const float* yp = y + (((size_t)(b * C + c0)) << 10) + n;
  float4 v0 = *(const float4*)yp;
  float4 v1 = *(const float4*)(yp + 1024);
  float q0[4] = {v0.x, v0.y, v0.z, v0.w};
  float q1[4] = {v1.x, v1.y, v1.z, v1.w};
  unsigned r[4];
#pragma unroll
  for (int k = 0; k < 4; ++k) {
    _Float16 h0 = (_Float16)fast_tanh((q0[k] - s0.x) * s0.y);
    _Float16 h1 = (_Float16)fast_tanh((q1[k] - s1.x) * s1.y);
    unsigned lo = (unsigned)__builtin_bit_cast(unsigned short, h0);
    unsigned hi = (unsigned)__builtin_bit_cast(unsigned short, h1);
    r[k] = lo | (hi << 16);
  }
  *(uint4*)(T16 + (((size_t)(b * nslot + s)) << 10) + n) = make_uint4(r[0], r[1], r[2], r[3]);
}

// ---------- MFMA KAN layer v10: Jacobi basis, pair-interleaved k, zero-pack A ----------
// A-frag dwords: {(1,1), q1-pair, q2-pair, q3-pair} — 5 pk ops, no pack/perm.
// Depth by occupancy regime (R9/R10 A-B evidence): DEPTH=4 for grid-starved
// layers (<=1 wave/SIMD nominal: L2/L3/L4 and L7/L8/L9), DEPTH=2 for TLP-rich
// layers (L5/L6). Runtime loop + named stage sets preserves prefetch distance.
template<int NBW, int DEPTH>
__global__ __launch_bounds__(NBW * 128, 2) void kan_mfma7(
    const unsigned* __restrict__ T16,  // (B, nslot, N) packed fp16 tanh pairs
    const half8* __restrict__ wh,
    const float* __restrict__ bias,    // (B, C_out) or nullptr
    float*       __restrict__ out,     // (B, C_out, N) fp32 or nullptr (L5 mode)
    float2*      __restrict__ spart,
    float*       __restrict__ stat_acc,
    unsigned*    __restrict__ max_acc,
    int C_in, int C_out)
{
  constexpr int BN = NBW * 64;
  const int nslot = C_in >> 1;
  __shared__ float sredS[BN][2], sredS2[BN][2], sredM[BN][2];

  const int t    = threadIdx.x;
  const int lane = t & 63;
  const int col  = lane & 15;
  const int quad = lane >> 4;
  const int wv   = t >> 6;
  const int wm   = wv & 1;
  const int wn   = wv >> 1;
  const int b    = blockIdx.x >> 3;
  const int n0   = (blockIdx.x & 7) << 7;
  const int o0   = blockIdx.y * BN;

  f32x4 acc[4][4];
#pragma unroll
  for (int i = 0; i < 4; ++i)
#pragma unroll
    for (int j = 0; j < 4; ++j)
#pragma unroll
      for (int k = 0; k < 4; ++k) acc[i][j][k] = 0.0f;

  const unsigned* Tp = T16 + (((size_t)(b * nslot + quad)) << 10) + n0 + (wm << 6) + col;
  const half8*    Bp = wh + (size_t)blockIdx.y * nslot * BN + (size_t)quad * BN + wn * 64 + col;

  const half2v c375  = {(_Float16)3.75f,  (_Float16)3.75f};
  const half2v cm075 = {(_Float16)-0.75f, (_Float16)-0.75f};
  const half2v c70   = {(_Float16)7.0f,   (_Float16)7.0f};
  const half2v cm30  = {(_Float16)-3.0f,  (_Float16)-3.0f};

#define KLOAD(TTR, BFR, J) do {                                            \
    const unsigned* tp_ = Tp + (((size_t)(unsigned)(J)) << 12);            \
    const half8*    bp_ = Bp + (size_t)(unsigned)(J) * (BN << 2);          \
    TTR[0] = tp_[0];  TTR[1] = tp_[16];                                    \
    TTR[2] = tp_[32]; TTR[3] = tp_[48];                                    \
    BFR[0] = bp_[0];  BFR[1] = bp_[16];                                    \
    BFR[2] = bp_[32]; BFR[3] = bp_[48];                                    \
  } while (0)

#define KSTEP(TTR, BFR) do {                                               \
    half8 af_[4];                                                          \
    _Pragma("unroll")                                                      \
    for (int fm_ = 0; fm_ < 4; ++fm_) {                                    \
      half2v tt = __builtin_bit_cast(half2v, TTR[fm_]);                    \
      half2v t2 = tt * tt;                                                 \
      half2v q1 = tt + tt;                                                 \
      half2v q2 = t2 * c375 + cm075;                                       \
      half2v q3 = tt * (t2 * c70 + cm30);                                  \
      af_[fm_] = __builtin_bit_cast(half8, make_uint4(                     \
          0x3C003C00u,                                                     \
          __builtin_bit_cast(unsigned, q1),                                \
          __builtin_bit_cast(unsigned, q2),                                \
          __builtin_bit_cast(unsigned, q3)));                              \
    }                                                                      \
    _Pragma("unroll")                                                      \
    for (int fm_ = 0; fm_ < 4; ++fm_) {                                    \
      _Pragma("unroll")                                                    \
      for (int fn_ = 0; fn_ < 4; ++fn_)                                    \
        acc[fm_][fn_] = __builtin_amdgcn_mfma_f32_16x16x32_f16(            \
            af_[fm_], BFR[fn_], acc[fm_][fn_], 0, 0, 0);                   \
    }                                                                      \
  } while (0)

  const int nIt = nslot >> 2;   // 8 / 16 / 32 / 64 — all % 4 == 0
  if constexpr (DEPTH == 2) {
    unsigned ttA[4], ttB[4];
    half8    bfA[4], bfB[4];
    KLOAD(ttA, bfA, 0);
    KLOAD(ttB, bfB, 1);
    int it = 0;
    for (; it + 3 < nIt; it += 2) {
      KSTEP(ttA, bfA); KLOAD(ttA, bfA, it + 2);
      KSTEP(ttB, bfB); KLOAD(ttB, bfB, it + 3);
    }
    KSTEP(ttA, bfA);
    KSTEP(ttB, bfB);
  } else {
    unsigned ttA[4], ttB[4], ttC[4], ttD[4];
    half8    bfA[4], bfB[4], bfC[4], bfD[4];
    KLOAD(ttA, bfA, 0);
    KLOAD(ttB, bfB, 1);
    KLOAD(ttC, bfC, 2);
    KLOAD(ttD, bfD, 3);
    int it = 0;
    for (; it + 7 < nIt; it += 4) {
      KSTEP(ttA, bfA); KLOAD(ttA, bfA, it + 4);
      KSTEP(ttB, bfB); KLOAD(ttB, bfB, it + 5);
      KSTEP(ttC, bfC); KLOAD(ttC, bfC, it + 6);
      KSTEP(ttD, bfD); KLOAD(ttD, bfD, it + 7);
    }
    KSTEP(ttA, bfA);
    KSTEP(ttB, bfB);
    KSTEP(ttC, bfC);
    KSTEP(ttD, bfD);
  }

#undef KLOAD
#undef KSTEP

  const float inv64 = 0.015625f;
#pragma unroll
  for (int fn = 0; fn < 4; ++fn) {
    const int cl = (wn << 6) + (fn << 4) + col;
    const int o  = o0 + cl;
    const float bb = bias ? bias[b * C_out + o] : 0.0f;
    float s = 0.f, s2 = 0.f, mx = -3.4e38f;
#pragma unroll
    for (int fm = 0; fm < 4; ++fm) {
      float v0 = acc[fm][fn][0] * inv64 + bb;
      float v1 = acc[fm][fn][1] * inv64 + bb;
      float v2 = acc[fm][fn][2] * inv64 + bb;
      float v3 = acc[fm][fn][3] * inv64 + bb;
      if (out) {
        *(float4*)(out + (((size_t)(b * C_out + o)) << 10) + n0 + (wm << 6) + (fm << 4) + (quad << 2)) =
            make_float4(v0, v1, v2, v3);
      }
      s  += v0 + v1 + v2 + v3;
      s2 += v0 * v0 + v1 * v1 + v2 * v2 + v3 * v3;
      mx  = fmaxf(fmaxf(v0, v1), fmaxf(fmaxf(v2, v3), mx));
    }
    s  += __shfl_down(s, 32);  s  += __shfl_down(s, 16);
    s2 += __shfl_down(s2, 32); s2 += __shfl_down(s2, 16);
    mx  = fmaxf(mx, __shfl_down(mx, 32)); mx = fmaxf(mx, __shfl_down(mx, 16));
    if (lane < 16) {
      sredS [cl][wm] = s;
      sredS2[cl][wm] = s2;
      sredM [cl][wm] = mx;
    }
  }
  __syncthreads();
  if (t < BN) {
    const int o = o0 + t;
    float s  = sredS [t][0] + sredS [t][1];
    float s2 = sredS2[t][0] + sredS2[t][1];
    if (out) {
      spart[(o << 8) + blockIdx.x] = make_float2(s, s2);
    } else {
      float mx = fmaxf(sredM[t][0], sredM[t][1]);
      atomicAdd(&stat_acc[o], s);
      atomicAdd(&stat_acc[C_out + o], s2);
      atomicMax(&max_acc[b * C_out + o], encf(mx));
    }
  }
}

// ---------- fp32 KAN layer (L1 only: C_in=2) ----------
template<int BM, int BN>
__global__ __launch_bounds__(256) void kan_gemm(
    const float*  __restrict__ in, const float2* __restrict__ stats,
    const float*  __restrict__ w, float* __restrict__ out,
    float2* __restrict__ spart, int C_in, int C_out)
{
  static_assert(BM * BN == 256 * 64, "8x8-per-thread tile requires BM*BN == 16384");
  constexpr int TM = BM / 8;
  constexpr int AE = 8 * BM / 256;
  constexpr int BE = 8 * BN / 256;
  __shared__ __align__(16) float As[32][BM];
  __shared__ __align__(16) float Bs[32][BN];

  const int t  = threadIdx.x;
  const int tpb = NPTS / BM;
  const int b  = blockIdx.x / tpb;
  const int n0 = (blockIdx.x % tpb) * BM;
  const int o0 = blockIdx.y * BN;
  const int tm = t % TM;
  const int to = t / TM;

  float acc[2][4][2][4];
#pragma unroll
  for (int a = 0; a < 2; ++a)
#pragma unroll
    for (int c = 0; c < 4; ++c)
#pragma unroll
      for (int d = 0; d < 2; ++d)
#pragma unroll
        for (int e = 0; e < 4; ++e) acc[a][c][d][e] = 0.0f;

  const int nch = (C_in + 7) >> 3;
  for (int ch = 0; ch < nch; ++ch) {
    const int i0 = ch << 3;
    __syncthreads();
#pragma unroll
    for (int r = 0; r < AE; ++r) {
      int e  = t + (r << 8);
      int il = e / BM, n = e % BM;
      int i  = i0 + il;
      float p0 = 0.f, p1 = 0.f, p2 = 0.f, p3 = 0.f;
      if (i < C_in) {
        float v = in[((size_t)(b * C_in + i) << 10) + n0 + n];
        if (stats) { float2 s = stats[i]; v = (v - s.x) * s.y; }
        jacobi4(fast_tanh(v), p0, p1, p2, p3);
      }
      As[(il << 2) + 0][n] = p0;
      As[(il << 2) + 1][n] = p1;
      As[(il << 2) + 2][n] = p2;
      As[(il << 2) + 3][n] = p3;
    }
#pragma unroll
    for (int r = 0; r < BE; ++r) {
      int e  = t + (r << 8);
      int il = e / BN, o = e % BN;
      int i  = i0 + il;
      float4 wv = make_float4(0.f, 0.f, 0.f, 0.f);
      if (i < C_in) wv = *(const float4*)(w + (((size_t)i * C_out + o0 + o) << 2));
      Bs[(il << 2) + 0][o] = wv.x;
      Bs[(il << 2) + 1][o] = wv.y;
      Bs[(il << 2) + 2][o] = wv.z;
      Bs[(il << 2) + 3][o] = wv.w;
    }
    __syncthreads();
#pragma unroll 8
    for (int k = 0; k < 32; ++k) {
      const float4 a0 = *(const float4*)&As[k][tm << 2];
      const float4 a1 = *(const float4*)&As[k][(BM / 2) + (tm << 2)];
      const float4 b0 = *(const float4*)&Bs[k][to << 2];
      const float4 b1 = *(const float4*)&Bs[k][(BN / 2) + (to << 2)];
      const float am[2][4] = {{a0.x, a0.y, a0.z, a0.w}, {a1.x, a1.y, a1.z, a1.w}};
      const float bo[2][4] = {{b0.x, b0.y, b0.z, b0.w}, {b1.x, b1.y, b1.z, b1.w}};
#pragma unroll
      for (int oh = 0; oh < 2; ++oh)
#pragma unroll
        for (int oj = 0; oj < 4; ++oj) {
          const float bv = bo[oh][oj];
#pragma unroll
          for (int mh = 0; mh < 2; ++mh)
#pragma unroll
            for (int mj = 0; mj < 4; ++mj)
              acc[oh][oj][mh][mj] = fmaf(bv, am[mh][mj], acc[oh][oj][mh][mj]);
        }
    }
  }

#pragma unroll
  for (int oh = 0; oh < 2; ++oh)
#pragma unroll
    for (int oj = 0; oj < 4; ++oj) {
      const int o = o0 + oh * (BN / 2) + (to << 2) + oj;
      float s = 0.f, s2 = 0.f;
#pragma unroll
      for (int mh = 0; mh < 2; ++mh) {
        float4 v = make_float4(acc[oh][oj][mh][0], acc[oh][oj][mh][1],
                               acc[oh][oj][mh][2], acc[oh][oj][mh][3]);
        *(float4*)(out + (((size_t)(b * C_out + o)) << 10) + n0 + mh * (BM / 2) + (tm << 2)) = v;
        s  += v.x + v.y + v.z + v.w;
        s2 += v.x * v.x + v.y * v.y + v.z * v.z + v.w * v.w;
      }
#pragma unroll
      for (int off = TM / 2; off > 0; off >>= 1) {
        s  += __shfl_down(s, off, TM);
        s2 += __shfl_down(s2, off, TM);
      }
      if (tm == 0) spart[(o << 8) + blockIdx.x] = make_float2(s, s2);
    }
}

// ---------- reduce per-block partials -> BN stats (L9 only; kan_final needs stats) ----------
__global__ __launch_bounds__(256) void bn_finalize2(
    const float2* __restrict__ spart, float2* __restrict__ stats, int C, int nxb)
{
  int c = blockIdx.x, t = threadIdx.x;
  float s = 0.f, s2 = 0.f;
  if (t < nxb) { float2 p = spart[(c << 8) + t]; s = p.x; s2 = p.y; }
#pragma unroll
  for (int off = 32; off > 0; off >>= 1) {
    s  += __shfl_down(s, off);
    s2 += __shfl_down(s2, off);
  }
  __shared__ float rs[4], rs2[4];
  int wid = t >> 6;
  if ((t & 63) == 0) { rs[wid] = s; rs2[wid] = s2; }
  __syncthreads();
  if (t == 0) {
    s  = rs[0] + rs[1] + rs[2] + rs[3];
    s2 = rs2[0] + rs2[1] + rs2[2] + rs2[3];
    float m   = s * (1.0f / NTOT);
    float var = s2 * (1.0f / NTOT) - m * m;
    stats[c] = make_float2(m, rsqrtf(var + 1e-5f));
  }
}

// ---------- finalize layer-5 stats from atomic accumulators ----------
__global__ void bn_finalize(const float* __restrict__ stat_acc,
                            float2* __restrict__ stats, int C) {
  int c = blockIdx.x * 256 + threadIdx.x;
  if (c < C) {
    float m   = stat_acc[c] * (1.0f / NTOT);
    float var = stat_acc[C + c] * (1.0f / NTOT) - m * m;
    stats[c] = make_float2(m, rsqrtf(var + 1e-5f));
  }
}

// ---------- global-feature branch of layer 6, parallel ----------
__global__ __launch_bounds__(256) void pool_const6p(
    const unsigned* __restrict__ max_acc, const float2* __restrict__ stats5,
    const float* __restrict__ w6, float* __restrict__ cst)
{
  __shared__ __align__(16) float4 P[32][64];
  const int t  = threadIdx.x;
  const int ot = blockIdx.x;
  const int c0 = blockIdx.y << 6;
#pragma unroll
  for (int it = 0; it < 8; ++it) {
    int idx = t + (it << 8);
    int b = idx >> 6, cl = idx & 63;
    int c = c0 + cl;
    float mx = decf(max_acc[(b << 10) + c]);
    float2 s = stats5[c];
    float tt = fast_tanh((mx - s.x) * s.y);
    float p0, p1, p2, p3; jacobi4(tt, p0, p1, p2, p3);
    P[b][cl] = make_float4(p0, p1, p2, p3);
  }
  __syncthreads();
  const int oL = t & 63;
  const int bg = t >> 6;
  const int o  = (ot << 6) + oL;
  float acc[8];
#pragma unroll
  for (int i = 0; i < 8; ++i) acc[i] = 0.f;
  for (int cl = 0; cl < 64; ++cl) {
    const float4 wv = *(const float4*)(w6 + (((size_t)(64 + c0 + cl) * 512 + o) << 2));
#pragma unroll
    for (int bb = 0; bb < 8; ++bb) {
      float4 p = P[(bg << 3) + bb][cl];
      acc[bb] += p.x * wv.x + p.y * wv.y + p.z * wv.z + p.w * wv.w;
    }
  }
#pragma unroll
  for (int bb = 0; bb < 8; ++bb)
    atomicAdd(&cst[(((bg << 3) + bb) << 9) + o], acc[bb]);
}

// ---------- final layer: C_in=128 fp32 -> C_out=3 fp32 ----------
__global__ __launch_bounds__(256) void kan_final(
    const float* __restrict__ in, const float2* __restrict__ stats,
    const float* __restrict__ w, float* __restrict__ out)
{
  int g = blockIdx.x * 256 + threadIdx.x;
  int b = g >> 10, n = g & 1023;
  float a0 = 0.f, a1 = 0.f, a2 = 0.f;
  for (int i = 0; i < 128; ++i) {
    float v = in[((size_t)(b * 128 + i) << 10) + n];
    float2 s = stats[i];
    float p0, p1, p2, p3; jacobi4(fast_tanh((v - s.x) * s.y), p0, p1, p2, p3);
    const float4 w0 = *(const float4*)(w + ((i * 3 + 0) << 2));
    const float4 w1 = *(const float4*)(w + ((i * 3 + 1) << 2));
    const float4 w2 = *(const float4*)(w + ((i * 3 + 2) << 2));
    a0 += p0 * w0.x + p1 * w0.y + p2 * w0.z + p3 * w0.w;
    a1 += p0 * w1.x + p1 * w1.y + p2 * w1.z + p3 * w1.w;
    a2 += p0 * w2.x + p1 * w2.y + p2 * w2.z + p3 * w2.w;
  }
  out[((b * 3 + 0) << 10) + n] = a0;
  out[((b * 3 + 1) << 10) + n] = a1;
  out[((b * 3 + 2) << 10) + n] = a2;
}

// ---------- launch ----------
extern "C" void kernel_launch(void* const* d_in, const int* in_sizes, int n_in,
                              void* d_out, int out_size, void* d_ws, size_t ws_size,
                              hipStream_t stream) {
  const float* x   = (const float*)d_in[0];
  const float* w1  = (const float*)d_in[1];
  const float* w2  = (const float*)d_in[2];
  const float* w3  = (const float*)d_in[3];
  const float* w4  = (const float*)d_in[4];
  const float* w5  = (const float*)d_in[5];
  const float* w6  = (const float*)d_in[6];
  const float* w7  = (const float*)d_in[7];
  const float* w8  = (const float*)d_in[8];
  const float* w9  = (const float*)d_in[9];
  const float* w10 = (const float*)d_in[10];

  float* ws = (float*)d_ws;
  // misc region (floats)
  float*    stat_acc = ws + 0;                      // 2048
  unsigned* maxenc   = (unsigned*)(ws + 2048);      // 32768
  float*    cst6     = ws + 34816;                  // 16384 (zeroed)
  float2*   spart    = (float2*)(ws + 51200);       // 131072 float2 -> ends 313344
  float2*   stats5   = (float2*)(ws + 313344);      // 1024
  float2*   stats9   = stats5 + 1024;               // 128
  // fp16 weight pool (half8 units) @ float offset 318464
  half8*    whbase = (half8*)(ws + 318464);
  half8*    h2 = whbase + 0;        // 32*64    = 2048
  half8*    h3 = whbase + 2048;     // 2048
  half8*    h4 = whbase + 4096;     // 32*128   = 4096
  half8*    h5 = whbase + 8192;     // 64*1024  = 65536
  half8*    h6 = whbase + 73728;    // 32*512   = 16384
  half8*    h7 = whbase + 90112;    // 256*256  = 65536
  half8*    h8 = whbase + 155648;   // 128*128  = 16384
  half8*    h9 = whbase + 172032;   // 64*128   = 8192  -> ends 720896 floats
  // data pool, liveness-aliased (units of MF = 1048576 floats; T16 sizes count u32 = float)
  const size_t MF = 1048576;
  float*    P   = ws + MF;
  unsigned* T2  = (unsigned*)(P + 0 * MF);
  float*    y1  = P + 1 * MF;
  unsigned* T1  = (unsigned*)(P + 3 * MF);
  float*    y2  = P + 1 * MF;
  float*    y3  = P + 1 * MF;
  unsigned* T3  = (unsigned*)(P + 3 * MF);
  float*    y4  = P + 4 * MF;
  unsigned* T4  = (unsigned*)(P + 1 * MF);
  float*    y6  = P + 3 * MF;
  unsigned* T6  = (unsigned*)(P + 19 * MF);
  float*    y7  = P + 0 * MF;
  unsigned* T7  = (unsigned*)(P + 8 * MF);
  float*    y8  = P + 0 * MF;
  unsigned* T8  = (unsigned*)(P + 4 * MF);
  float*    y9  = P + 12 * MF;

  dim3 blk(256);
  zero_ws<<<200, blk, 0, stream>>>((unsigned*)ws, 51200);

  // batched weight preconversion: one dispatch for all 8 layers (pair-interleave)
  ConvArgs ca;
  ca.w[0] = w2;  ca.w[1] = w3;  ca.w[2] = w4;  ca.w[3] = w5;
  ca.w[4] = w6;  ca.w[5] = w7;  ca.w[6] = w8;  ca.w[7] = w9;
  const int cins[8]  = {64, 64, 64, 128, 64, 512, 256, 128};
  const int couts[8] = {64, 64, 128, 1024, 512, 256, 128, 128};
  const int bns[8]   = {64, 64, 128, 128, 128, 128, 128, 128};
  const int whof[8]  = {0, 2048, 4096, 8192, 73728, 90112, 155648, 172032};
  int acc_blk = 0;
  for (int i = 0; i < 8; ++i) {
    ca.cin[i] = cins[i]; ca.cout[i] = couts[i]; ca.bn[i] = bns[i]; ca.whoff[i] = whof[i];
    ca.blk0[i] = acc_blk;
    acc_blk += (cins[i] >> 1) * couts[i] / 256;   // nslot*C_out elements / 256 threads
  }
  conv_w16_all<<<acc_blk, blk, 0, stream>>>(ca, whbase);

  // L1: 2 -> 64 fp32 (spart nxb = 128)
  kan_gemm<256, 64><<<dim3(128, 1), blk, 0, stream>>>(x, nullptr, w1, y1, spart, 2, 64);
  act_tanh16s<<<32 * 32, blk, 0, stream>>>(y1, spart, T1, 64, 128);
  // L2: 64 -> 64 (grid-starved: 2 waves/CU -> depth 4)
  kan_mfma7<1, 4><<<dim3(256, 1), 128, 0, stream>>>(T1, h2, nullptr, y2, spart, nullptr, nullptr, 64, 64);
  act_tanh16s<<<32 * 32, blk, 0, stream>>>(y2, spart, T2, 64, 256);   // T2 kept for L6
  // L3: 64 -> 64 (depth 4)
  kan_mfma7<1, 4><<<dim3(256, 1), 128, 0, stream>>>(T2, h3, nullptr, y3, spart, nullptr, nullptr, 64, 64);
  act_tanh16s<<<32 * 32, blk, 0, stream>>>(y3, spart, T3, 64, 256);
  // L4: 64 -> 128 (grid-starved: 1 wave/SIMD -> depth 4)
  kan_mfma7<2, 4><<<dim3(256, 1), blk, 0, stream>>>(T3, h4, nullptr, y4, spart, nullptr, nullptr, 64, 128);
  act_tanh16s<<<32 * 64, blk, 0, stream>>>(y4, spart, T4, 128, 256);
  // L5: 128 -> 1024, fused stats + maxpool (TLP-rich: depth 2)
  kan_mfma7<2, 2><<<dim3(256, 8), blk, 0, stream>>>(T4, h5, nullptr, nullptr, nullptr, stat_acc, maxenc, 128, 1024);
  bn_finalize<<<4, blk, 0, stream>>>(stat_acc, stats5, 1024);
  // gf branch of layer 6
  pool_const6p<<<dim3(8, 16), blk, 0, stream>>>(maxenc, stats5, w6, cst6);
  // L6: 64 (local, T2) -> 512 + gf bias (TLP-rich: depth 2)
  kan_mfma7<2, 2><<<dim3(256, 4), blk, 0, stream>>>(T2, h6, cst6, y6, spart, nullptr, nullptr, 64, 512);
  act_tanh16s<<<32 * 256, blk, 0, stream>>>(y6, spart, T6, 512, 256);
  // L7: 512 -> 256 (depth 4)
  kan_mfma7<2, 4><<<dim3(256, 2), blk, 0, stream>>>(T6, h7, nullptr, y7, spart, nullptr, nullptr, 512, 256);
  act_tanh16s<<<32 * 128, blk, 0, stream>>>(y7, spart, T7, 256, 256);
  // L8: 256 -> 128 (depth 4)
  kan_mfma7<2, 4><<<dim3(256, 1), blk, 0, stream>>>(T7, h8, nullptr, y8, spart, nullptr, nullptr, 256, 128);
  act_tanh16s<<<32 * 64, blk, 0, stream>>>(y8, spart, T8, 128, 256);
  // L9: 128 -> 128 (depth 4); stats9 still needed by kan_final
  kan_mfma7<2, 4><<<dim3(256, 1), blk, 0, stream>>>(T8, h9, nullptr, y9, spart, nullptr, nullptr, 128, 128);
  bn_finalize2<<<128, blk, 0, stream>>>(spart, stats9, 128, 256);
  // L10: 128 -> 3 (tanh+Jacobi inline, fp32)
  kan_final<<<128, blk, 0, stream>>>(y9, stats9, w10, (float*)d_out);
}